// Round 3
// baseline (268.372 us; speedup 1.0000x reference)
//
#include <hip/hip_runtime.h>
#include <stdint.h>

// ---------------- types & helpers ----------------
typedef short sh4 __attribute__((ext_vector_type(4)));
typedef short short8 __attribute__((ext_vector_type(8)));
typedef float f32x4 __attribute__((ext_vector_type(4)));
typedef _Float16 half4 __attribute__((ext_vector_type(4)));
typedef _Float16 half8 __attribute__((ext_vector_type(8)));
typedef unsigned int uint2v __attribute__((ext_vector_type(2)));

__device__ __forceinline__ short f2h(float f) {
    _Float16 h = (_Float16)f;
    return __builtin_bit_cast(short, h);
}

__device__ __forceinline__ f32x4 mfma_k32(short8 a, short8 b, f32x4 c) {
    return __builtin_amdgcn_mfma_f32_16x16x32_f16(
        __builtin_bit_cast(half8, a), __builtin_bit_cast(half8, b), c, 0, 0, 0);
}
__device__ __forceinline__ f32x4 mfma_k16(half4 a, half4 b, f32x4 c) {
    return __builtin_amdgcn_mfma_f32_16x16x16f16(a, b, c, 0, 0, 0);
}

// Problem constants: B=4, C=256, H=W=128 (PX=16384), inner=256, heads=8, c/head=32,
// patch=8 -> keys=256, conv K-dim = 256*64 = 16384.

// ---------------- pack kernels: 64x64 fp32 tile transpose -> f16 ----------------
__device__ __forceinline__ void transpose64(const float* __restrict__ src,
                                            short* __restrict__ dst,
                                            int srcSlowStride, int dstRowStride) {
    __shared__ float tile[64][65];
    const int t = threadIdx.x;
#pragma unroll
    for (int i = 0; i < 16; ++i) {
        int idx = i * 256 + t;
        int fast = idx & 63, slow = idx >> 6;
        tile[slow][fast] = src[(long)slow * srcSlowStride + fast];
    }
    __syncthreads();
#pragma unroll
    for (int i = 0; i < 2; ++i) {
        int ch = i * 256 + t;
        int fast = ch >> 3, sg = ch & 7;
        short8 v;
#pragma unroll
        for (int j = 0; j < 8; ++j) v[j] = f2h(tile[sg * 8 + j][fast]);
        *(short8*)(dst + (long)fast * dstRowStride + sg * 8) = v;
    }
}

// x: [4][256][16384] fp32 (NCHW) -> xn: [4][16384][256] f16 (NHWC)
__global__ __launch_bounds__(256) void k_pack_x(const float* __restrict__ x,
                                                short* __restrict__ xn) {
    int bi = blockIdx.x;                 // 4096 = 4b * 256pxt * 4ct
    int ct = bi & 3, pxt = (bi >> 2) & 255, b = bi >> 10;
    const float* src = x + (((long)(b * 256 + ct * 64)) << 14) + (long)pxt * 64;
    short* dst = xn + (((long)(b << 14) + pxt * 64) * 256) + ct * 64;
    transpose64(src, dst, 16384, 256);
}

// Wk/Wv: [256][256][64] fp32 -> wp: [512][64][256] f16 (oc<256: k, else v), K order (dydx, c)
__global__ __launch_bounds__(256) void k_pack_w(const float* __restrict__ wk,
                                                const float* __restrict__ wv,
                                                short* __restrict__ wp) {
    int bi = blockIdx.x;                 // 2048 = 512oc * 4ct
    int ct = bi & 3, oc = bi >> 2;
    const float* base = (oc < 256) ? (wk + (long)oc * 16384) : (wv + (long)(oc - 256) * 16384);
    const float* src = base + ct * 4096; // + c0*64
    short* dst = wp + (long)oc * 16384 + ct * 64;
    transpose64(src, dst, 64, 256);
}

// Wq: [256][256] fp32 -> f16 (layout preserved: [oc][c])
__global__ __launch_bounds__(256) void k_pack_wq(const float* __restrict__ wq,
                                                 short* __restrict__ wqp) {
    int i = blockIdx.x * 256 + threadIdx.x; // grid 256 -> 65536
    wqp[i] = f2h(wq[i]);
}

// ---------------- K/V conv as GEMM ----------------
// C[patch 1024][oc 512] = A[patch][k 16384] * B[k][oc], K-split 16 -> partials
// block: 256(M) x 128(N) x Kchunk 1024 (16 iters of BK=64), 8 waves (512 thr)
__global__ __launch_bounds__(512) void k_kv_gemm(const short* __restrict__ xn,
                                                 const short* __restrict__ wp,
                                                 float* __restrict__ part) {
    __shared__ short Al[256 * 64]; // rows 128B = 8 granules, swizzled
    __shared__ short Bl[128 * 64];
    int bid = blockIdx.x;                       // 256
    int wg = (bid & 7) * 32 + (bid >> 3);       // XCD-contiguous swizzle (256 = 8*32)
    int nb = wg & 3, pm = (wg >> 2) & 3, kc = wg >> 4;
    int t = threadIdx.x, l = t & 63, w = t >> 6;
    int wm = w >> 1, wn = w & 1;

    f32x4 acc[4][4];
#pragma unroll
    for (int mt = 0; mt < 4; ++mt)
#pragma unroll
        for (int nt = 0; nt < 4; ++nt) acc[mt][nt] = (f32x4){0.f, 0.f, 0.f, 0.f};

    for (int kk = 0; kk < 16; ++kk) {
        short8 va[4], vb[2];
#pragma unroll
        for (int i = 0; i < 4; ++i) {           // A: 2048 granules
            int g = i * 512 + t;
            int row = g >> 3, lg = g & 7;
            int patch = pm * 256 + row;
            int kg = kc * 1024 + kk * 64 + lg * 8;
            int dydx = kg >> 8, cc = kg & 255;
            int bb = patch >> 8, pid = patch & 255;
            int ph = pid >> 4, pw = pid & 15;
            int px = (ph * 8 + (dydx >> 3)) * 128 + pw * 8 + (dydx & 7);
            va[i] = *(const short8*)(xn + ((long)(bb << 14) + px) * 256 + cc);
        }
#pragma unroll
        for (int i = 0; i < 2; ++i) {           // B: 1024 granules
            int g = i * 512 + t;
            int row = g >> 3, lg = g & 7;
            int oc = nb * 128 + row;
            int kg = kc * 1024 + kk * 64 + lg * 8;
            vb[i] = *(const short8*)(wp + (long)oc * 16384 + kg);
        }
#pragma unroll
        for (int i = 0; i < 4; ++i) {
            int g = i * 512 + t;
            int row = g >> 3, lg = g & 7;
            *(short8*)(Al + row * 64 + ((lg ^ (row & 7)) * 8)) = va[i];
        }
#pragma unroll
        for (int i = 0; i < 2; ++i) {
            int g = i * 512 + t;
            int row = g >> 3, lg = g & 7;
            *(short8*)(Bl + row * 64 + ((lg ^ (row & 7)) * 8)) = vb[i];
        }
        __syncthreads();
#pragma unroll
        for (int ks = 0; ks < 2; ++ks) {
            short8 af[4], bf[4];
#pragma unroll
            for (int mt = 0; mt < 4; ++mt) {
                int row = wm * 64 + mt * 16 + (l & 15);
                int lg = ks * 4 + (l >> 4);
                af[mt] = *(const short8*)(Al + row * 64 + ((lg ^ (row & 7)) * 8));
            }
#pragma unroll
            for (int nt = 0; nt < 4; ++nt) {
                int row = wn * 64 + nt * 16 + (l & 15);
                int lg = ks * 4 + (l >> 4);
                bf[nt] = *(const short8*)(Bl + row * 64 + ((lg ^ (row & 7)) * 8));
            }
#pragma unroll
            for (int mt = 0; mt < 4; ++mt)
#pragma unroll
                for (int nt = 0; nt < 4; ++nt)
                    acc[mt][nt] = mfma_k32(af[mt], bf[nt], acc[mt][nt]);
        }
        __syncthreads();
    }
    // D: row(patch) = (l>>4)*4+r (+16mt+64wm+256pm), col(oc) = (l&15) (+16nt+64wn+128nb)
#pragma unroll
    for (int mt = 0; mt < 4; ++mt) {
        int patch = pm * 256 + wm * 64 + mt * 16 + ((l >> 4) * 4);
#pragma unroll
        for (int nt = 0; nt < 4; ++nt) {
            int oc = nb * 128 + wn * 64 + nt * 16 + (l & 15);
#pragma unroll
            for (int r = 0; r < 4; ++r)
                part[((long)kc * 1024 + patch + r) * 512 + oc] = acc[mt][nt][r];
        }
    }
}

// reduce partials, add bias, pack k -> [b][h][key][c], v -> [b][h][c][key] (f16)
__global__ __launch_bounds__(256) void k_kv_fin(const float* __restrict__ part,
                                                const float* __restrict__ bk,
                                                const float* __restrict__ bv,
                                                short* __restrict__ kp,
                                                short* __restrict__ vp) {
    int idx = blockIdx.x * 256 + threadIdx.x;   // 524288 = 1024patch * 512oc
    int oc = idx & 511, patch = idx >> 9;
    float s = 0.f;
#pragma unroll
    for (int kc = 0; kc < 16; ++kc) s += part[(long)kc * 524288 + idx];
    int b = patch >> 8, key = patch & 255;
    if (oc < 256) {
        s += bk[oc];
        kp[(((long)(b * 8 + (oc & 7)) * 256) + key) * 32 + (oc >> 3)] = f2h(s);
    } else {
        int o = oc - 256;
        s += bv[o];
        vp[(((long)(b * 8 + (o & 7)) * 32) + (o >> 3)) * 256 + key] = f2h(s);
    }
}

// ---------------- Q conv (1x1) as GEMM ----------------
// D[oc 256][px 128] per block; q out layout [b][h 8][c 32][px 16384] f16
__global__ __launch_bounds__(256) void k_q_gemm(const short* __restrict__ xn,
                                                const short* __restrict__ wqp,
                                                const float* __restrict__ bq,
                                                short* __restrict__ qp) {
    __shared__ short Xl[128 * 256]; // [px][c], rows 512B = 32 granules, swizzled
    int bi = blockIdx.x;            // 512 = 4b * 128tiles
    int b = bi >> 7, tile = bi & 127;
    long px0 = (long)tile * 128;
    int t = threadIdx.x, l = t & 63, w = t >> 6;
#pragma unroll
    for (int i = 0; i < 16; ++i) {
        int g = i * 256 + t;        // 4096 granules
        int px = g >> 5, lg = g & 31;
        short8 v = *(const short8*)(xn + (((long)(b << 14)) + px0 + px) * 256 + lg * 8);
        *(short8*)(Xl + px * 256 + ((lg ^ (px & 7)) * 8)) = v;
    }
    __syncthreads();

    f32x4 acc[16][2];
#pragma unroll
    for (int mt = 0; mt < 16; ++mt) {
        acc[mt][0] = (f32x4){0.f, 0.f, 0.f, 0.f};
        acc[mt][1] = (f32x4){0.f, 0.f, 0.f, 0.f};
    }
#pragma unroll
    for (int kstep = 0; kstep < 8; ++kstep) {
        short8 bf[2];
#pragma unroll
        for (int nt = 0; nt < 2; ++nt) {
            int px = w * 32 + nt * 16 + (l & 15);
            int lg = kstep * 4 + (l >> 4);
            bf[nt] = *(const short8*)(Xl + px * 256 + ((lg ^ (px & 7)) * 8));
        }
#pragma unroll
        for (int mt = 0; mt < 16; ++mt) {
            short8 af = *(const short8*)(wqp + (mt * 16 + (l & 15)) * 256 + kstep * 32 + (l >> 4) * 8);
#pragma unroll
            for (int nt = 0; nt < 2; ++nt)
                acc[mt][nt] = mfma_k32(af, bf[nt], acc[mt][nt]);
        }
    }
    // D: row(oc) = (l>>4)*4+r+16mt, col(px) = (l&15)+16nt+32w -> write [b][h][c][px]
#pragma unroll
    for (int mt = 0; mt < 16; ++mt)
#pragma unroll
        for (int nt = 0; nt < 2; ++nt)
#pragma unroll
            for (int r = 0; r < 4; ++r) {
                int oc = mt * 16 + (l >> 4) * 4 + r;
                long px = px0 + w * 32 + nt * 16 + (l & 15);
                float v = acc[mt][nt][r] + bq[oc];
                qp[((long)((b * 8 + (oc & 7)) * 32 + (oc >> 3))) * 16384 + px] = f2h(v);
            }
}

// ---------------- fused attention (v2: no LDS, 1 head/block) ----------------
// grid 4096 = 4b * 8h * 128 tiles; block 256 thr = 4 waves x 32 px.
// QK^T swapped: D[key][px] via 16x16x32; P feeds PV directly as B-operand of
// 16x16x16 (k-groups of 4 == D r-groups of 4). V A-frags: direct 8B global
// loads from vp[b][h][c][key]. Output D[c][px] -> coalesced 64B runs.
__global__ __launch_bounds__(256) void k_attn(const short* __restrict__ qp,
                                              const short* __restrict__ kp,
                                              const short* __restrict__ vp,
                                              float* __restrict__ out) {
    int bi = blockIdx.x;
    int tile = bi & 127, h = (bi >> 7) & 7, b = bi >> 10;
    int bh = b * 8 + h;
    long px0 = (long)tile * 128;
    int t = threadIdx.x, l = t & 63, w = t >> 6;
    int low = l & 15, q = l >> 4;

    const short* kbase = kp + (long)bh * 256 * 32;    // [key][c32]
    const short* vbase = vp + (long)bh * 32 * 256;    // [c32][key256]
    const short* qbase = qp + (long)bh * 32 * 16384;  // [c32][px]

#pragma unroll 1
    for (int nt = 0; nt < 2; ++nt) {
        long px = px0 + w * 32 + nt * 16 + low;
        // q B-frag (16x16x32): n=px, k=c=q*8+j
        short8 bq2;
        const short* qq = qbase + (long)(q * 8) * 16384 + px;
#pragma unroll
        for (int j = 0; j < 8; ++j) bq2[j] = qq[(long)j * 16384];

        // QK^T: d[mt] covers keys mt*16 + q*4 + r, col = px
        f32x4 d[16];
#pragma unroll
        for (int mt = 0; mt < 16; ++mt) d[mt] = (f32x4){0.f, 0.f, 0.f, 0.f};
#pragma unroll
        for (int mt = 0; mt < 16; ++mt) {
            short8 ak = *(const short8*)(kbase + (mt * 16 + low) * 32 + q * 8);
            d[mt] = mfma_k32(ak, bq2, d[mt]);
        }

        // softmax over 256 keys: 64 lane-local + xor over lane bits 4,5
        float m = -1e30f;
#pragma unroll
        for (int mt = 0; mt < 16; ++mt)
#pragma unroll
            for (int r = 0; r < 4; ++r) m = fmaxf(m, d[mt][r]);
        m = fmaxf(m, __shfl_xor(m, 16));
        m = fmaxf(m, __shfl_xor(m, 32));
        float s = 0.f;
#pragma unroll
        for (int mt = 0; mt < 16; ++mt)
#pragma unroll
            for (int r = 0; r < 4; ++r) {
                float p = __expf(d[mt][r] - m);
                d[mt][r] = p;
                s += p;
            }
        s += __shfl_xor(s, 16);
        s += __shfl_xor(s, 32);
        float inv = 1.0f / s;

        // PV: o2[ct] = sum_kc V[c][16keys] x P[16keys][px] (16x16x16)
        f32x4 o2[2];
        o2[0] = (f32x4){0.f, 0.f, 0.f, 0.f};
        o2[1] = (f32x4){0.f, 0.f, 0.f, 0.f};
#pragma unroll
        for (int kc = 0; kc < 16; ++kc) {
            uint2v uu;
            uu[0] = __builtin_bit_cast(unsigned int,
                      __builtin_amdgcn_cvt_pkrtz(d[kc][0], d[kc][1]));
            uu[1] = __builtin_bit_cast(unsigned int,
                      __builtin_amdgcn_cvt_pkrtz(d[kc][2], d[kc][3]));
            half4 pb = __builtin_bit_cast(half4, uu);
#pragma unroll
            for (int ct = 0; ct < 2; ++ct) {
                const short* va = vbase + (ct * 16 + low) * 256 + kc * 16 + q * 4;
                half4 av = __builtin_bit_cast(half4, *(const sh4*)va);
                o2[ct] = mfma_k16(av, pb, o2[ct]);
            }
        }
        // write out [b][c*8+h][px] fp32; D row=c=ct*16+q*4+r, col=px
#pragma unroll
        for (int ct = 0; ct < 2; ++ct)
#pragma unroll
            for (int r = 0; r < 4; ++r) {
                int c = ct * 16 + q * 4 + r;
                out[(((long)(b * 256 + c * 8 + h)) << 14) + px] = o2[ct][r] * inv;
            }
    }
}

// ---------------- launch ----------------
extern "C" void kernel_launch(void* const* d_in, const int* in_sizes, int n_in,
                              void* d_out, int out_size, void* d_ws, size_t ws_size,
                              hipStream_t stream) {
    const float* x  = (const float*)d_in[0];
    const float* Wq = (const float*)d_in[1];
    const float* bq = (const float*)d_in[2];
    const float* Wk = (const float*)d_in[3];
    const float* bk = (const float*)d_in[4];
    const float* Wv = (const float*)d_in[5];
    const float* bv = (const float*)d_in[6];
    float* out = (float*)d_out;

    char* ws = (char*)d_ws;
    const size_t OFF_XN = 0;             // 33,554,432  x NHWC f16
    const size_t OFF_Q  = 33554432;      // 33,554,432  q [b][h][c][px] f16
    const size_t OFF_WP = 67108864;      // 16,777,216  w_pack [512][16384] f16
    const size_t OFF_WQ = 83886080;      //    131,072  wq f16
    const size_t OFF_KP = 84017152;      //    524,288  k_pack f16
    const size_t OFF_VP = 84541440;      //    524,288  v_pack f16
    const size_t OFF_PT = 85065728;      // 33,554,432  partials fp32 [16][1024][512]
    const size_t NEEDED = 118620160;
    if (ws_size < NEEDED) return;        // fail loudly via validation

    short* xn  = (short*)(ws + OFF_XN);
    short* qp  = (short*)(ws + OFF_Q);
    short* wp  = (short*)(ws + OFF_WP);
    short* wqp = (short*)(ws + OFF_WQ);
    short* kp  = (short*)(ws + OFF_KP);
    short* vp  = (short*)(ws + OFF_VP);
    float* part= (float*)(ws + OFF_PT);

    k_pack_x <<<dim3(4096), dim3(256), 0, stream>>>(x, xn);
    k_pack_w <<<dim3(2048), dim3(256), 0, stream>>>(Wk, Wv, wp);
    k_pack_wq<<<dim3(256),  dim3(256), 0, stream>>>(Wq, wqp);
    k_kv_gemm<<<dim3(256),  dim3(512), 0, stream>>>(xn, wp, part);
    k_kv_fin <<<dim3(2048), dim3(256), 0, stream>>>(part, bk, bv, kp, vp);
    k_q_gemm <<<dim3(512),  dim3(256), 0, stream>>>(xn, wqp, bq, qp);
    k_attn   <<<dim3(4096), dim3(256), 0, stream>>>(qp, kp, vp, out);
}

// Round 5
// 217.305 us; speedup vs baseline: 1.2350x; 1.2350x over previous
//
#include <hip/hip_runtime.h>
#include <stdint.h>

// ---------------- types & helpers ----------------
typedef short sh4 __attribute__((ext_vector_type(4)));
typedef short short8 __attribute__((ext_vector_type(8)));
typedef float f32x4 __attribute__((ext_vector_type(4)));
typedef _Float16 half4 __attribute__((ext_vector_type(4)));
typedef _Float16 half8 __attribute__((ext_vector_type(8)));
typedef unsigned int uint2v __attribute__((ext_vector_type(2)));

__device__ __forceinline__ short f2h(float f) {
    _Float16 h = (_Float16)f;
    return __builtin_bit_cast(short, h);
}

__device__ __forceinline__ f32x4 mfma_k32(short8 a, short8 b, f32x4 c) {
    return __builtin_amdgcn_mfma_f32_16x16x32_f16(
        __builtin_bit_cast(half8, a), __builtin_bit_cast(half8, b), c, 0, 0, 0);
}
__device__ __forceinline__ f32x4 mfma_k16(half4 a, half4 b, f32x4 c) {
    return __builtin_amdgcn_mfma_f32_16x16x16f16(a, b, c, 0, 0, 0);
}

// Problem constants: B=4, C=256, H=W=128 (PX=16384), inner=256, heads=8, c/head=32,
// patch=8 -> keys=256, conv K-dim = 256*64 = 16384.

// ---------------- pack kernels: 64x64 fp32 tile transpose -> f16 ----------------
__device__ __forceinline__ void transpose64(const float* __restrict__ src,
                                            short* __restrict__ dst,
                                            int srcSlowStride, int dstRowStride) {
    __shared__ float tile[64][65];
    const int t = threadIdx.x;
#pragma unroll
    for (int i = 0; i < 16; ++i) {
        int idx = i * 256 + t;
        int fast = idx & 63, slow = idx >> 6;
        tile[slow][fast] = src[(long)slow * srcSlowStride + fast];
    }
    __syncthreads();
#pragma unroll
    for (int i = 0; i < 2; ++i) {
        int ch = i * 256 + t;
        int fast = ch >> 3, sg = ch & 7;
        short8 v;
#pragma unroll
        for (int j = 0; j < 8; ++j) v[j] = f2h(tile[sg * 8 + j][fast]);
        *(short8*)(dst + (long)fast * dstRowStride + sg * 8) = v;
    }
}

// x: [4][256][16384] fp32 (NCHW) -> xn: [4][16384][256] f16 (NHWC)
__global__ __launch_bounds__(256) void k_pack_x(const float* __restrict__ x,
                                                short* __restrict__ xn) {
    int bi = blockIdx.x;                 // 4096 = 4b * 256pxt * 4ct
    int ct = bi & 3, pxt = (bi >> 2) & 255, b = bi >> 10;
    const float* src = x + (((long)(b * 256 + ct * 64)) << 14) + (long)pxt * 64;
    short* dst = xn + (((long)(b << 14) + pxt * 64) * 256) + ct * 64;
    transpose64(src, dst, 16384, 256);
}

// Wk/Wv: [256][256][64] fp32 -> wp: [512][64][256] f16 (oc<256: k, else v), K order (dydx, c)
__global__ __launch_bounds__(256) void k_pack_w(const float* __restrict__ wk,
                                                const float* __restrict__ wv,
                                                short* __restrict__ wp) {
    int bi = blockIdx.x;                 // 2048 = 512oc * 4ct
    int ct = bi & 3, oc = bi >> 2;
    const float* base = (oc < 256) ? (wk + (long)oc * 16384) : (wv + (long)(oc - 256) * 16384);
    const float* src = base + ct * 4096; // + c0*64
    short* dst = wp + (long)oc * 16384 + ct * 64;
    transpose64(src, dst, 64, 256);
}

// Wq: [256][256] fp32 -> f16 (layout preserved: [oc][c])
__global__ __launch_bounds__(256) void k_pack_wq(const float* __restrict__ wq,
                                                 short* __restrict__ wqp) {
    int i = blockIdx.x * 256 + threadIdx.x; // grid 256 -> 65536
    wqp[i] = f2h(wq[i]);
}

// ---------------- K/V conv as GEMM ----------------
// C[patch 1024][oc 512] = A[patch][k 16384] * B[k][oc], K-split 16 -> partials
// block: 256(M) x 128(N) x Kchunk 1024 (16 iters of BK=64), 8 waves (512 thr)
__global__ __launch_bounds__(512) void k_kv_gemm(const short* __restrict__ xn,
                                                 const short* __restrict__ wp,
                                                 float* __restrict__ part) {
    __shared__ short Al[256 * 64]; // rows 128B = 8 granules, swizzled
    __shared__ short Bl[128 * 64];
    int bid = blockIdx.x;                       // 256
    int wg = (bid & 7) * 32 + (bid >> 3);       // XCD-contiguous swizzle (256 = 8*32)
    int nb = wg & 3, pm = (wg >> 2) & 3, kc = wg >> 4;
    int t = threadIdx.x, l = t & 63, w = t >> 6;
    int wm = w >> 1, wn = w & 1;

    f32x4 acc[4][4];
#pragma unroll
    for (int mt = 0; mt < 4; ++mt)
#pragma unroll
        for (int nt = 0; nt < 4; ++nt) acc[mt][nt] = (f32x4){0.f, 0.f, 0.f, 0.f};

    for (int kk = 0; kk < 16; ++kk) {
        short8 va[4], vb[2];
#pragma unroll
        for (int i = 0; i < 4; ++i) {           // A: 2048 granules
            int g = i * 512 + t;
            int row = g >> 3, lg = g & 7;
            int patch = pm * 256 + row;
            int kg = kc * 1024 + kk * 64 + lg * 8;
            int dydx = kg >> 8, cc = kg & 255;
            int bb = patch >> 8, pid = patch & 255;
            int ph = pid >> 4, pw = pid & 15;
            int px = (ph * 8 + (dydx >> 3)) * 128 + pw * 8 + (dydx & 7);
            va[i] = *(const short8*)(xn + ((long)(bb << 14) + px) * 256 + cc);
        }
#pragma unroll
        for (int i = 0; i < 2; ++i) {           // B: 1024 granules
            int g = i * 512 + t;
            int row = g >> 3, lg = g & 7;
            int oc = nb * 128 + row;
            int kg = kc * 1024 + kk * 64 + lg * 8;
            vb[i] = *(const short8*)(wp + (long)oc * 16384 + kg);
        }
#pragma unroll
        for (int i = 0; i < 4; ++i) {
            int g = i * 512 + t;
            int row = g >> 3, lg = g & 7;
            *(short8*)(Al + row * 64 + ((lg ^ (row & 7)) * 8)) = va[i];
        }
#pragma unroll
        for (int i = 0; i < 2; ++i) {
            int g = i * 512 + t;
            int row = g >> 3, lg = g & 7;
            *(short8*)(Bl + row * 64 + ((lg ^ (row & 7)) * 8)) = vb[i];
        }
        __syncthreads();
#pragma unroll
        for (int ks = 0; ks < 2; ++ks) {
            short8 af[4], bf[4];
#pragma unroll
            for (int mt = 0; mt < 4; ++mt) {
                int row = wm * 64 + mt * 16 + (l & 15);
                int lg = ks * 4 + (l >> 4);
                af[mt] = *(const short8*)(Al + row * 64 + ((lg ^ (row & 7)) * 8));
            }
#pragma unroll
            for (int nt = 0; nt < 4; ++nt) {
                int row = wn * 64 + nt * 16 + (l & 15);
                int lg = ks * 4 + (l >> 4);
                bf[nt] = *(const short8*)(Bl + row * 64 + ((lg ^ (row & 7)) * 8));
            }
#pragma unroll
            for (int mt = 0; mt < 4; ++mt)
#pragma unroll
                for (int nt = 0; nt < 4; ++nt)
                    acc[mt][nt] = mfma_k32(af[mt], bf[nt], acc[mt][nt]);
        }
        __syncthreads();
    }
    // D: row(patch) = (l>>4)*4+r (+16mt+64wm+256pm), col(oc) = (l&15) (+16nt+64wn+128nb)
#pragma unroll
    for (int mt = 0; mt < 4; ++mt) {
        int patch = pm * 256 + wm * 64 + mt * 16 + ((l >> 4) * 4);
#pragma unroll
        for (int nt = 0; nt < 4; ++nt) {
            int oc = nb * 128 + wn * 64 + nt * 16 + (l & 15);
#pragma unroll
            for (int r = 0; r < 4; ++r)
                part[((long)kc * 1024 + patch + r) * 512 + oc] = acc[mt][nt][r];
        }
    }
}

// reduce partials, add bias, pack k -> [b][h][key][c], v -> [b][h][c][key] (f16)
__global__ __launch_bounds__(256) void k_kv_fin(const float* __restrict__ part,
                                                const float* __restrict__ bk,
                                                const float* __restrict__ bv,
                                                short* __restrict__ kp,
                                                short* __restrict__ vp) {
    int idx = blockIdx.x * 256 + threadIdx.x;   // 524288 = 1024patch * 512oc
    int oc = idx & 511, patch = idx >> 9;
    float s = 0.f;
#pragma unroll
    for (int kc = 0; kc < 16; ++kc) s += part[(long)kc * 524288 + idx];
    int b = patch >> 8, key = patch & 255;
    if (oc < 256) {
        s += bk[oc];
        kp[(((long)(b * 8 + (oc & 7)) * 256) + key) * 32 + (oc >> 3)] = f2h(s);
    } else {
        int o = oc - 256;
        s += bv[o];
        vp[(((long)(b * 8 + (o & 7)) * 32) + (o >> 3)) * 256 + key] = f2h(s);
    }
}

// ---------------- Q conv (1x1) as GEMM ----------------
// MFMA computes D[oc 256][px 128]; epilogue transposes through LDS so q is
// stored as [b][h 8][px 16384][c 32] f16 (attention reads 16B per lane).
__global__ __launch_bounds__(256) void k_q_gemm(const short* __restrict__ xn,
                                                const short* __restrict__ wqp,
                                                const float* __restrict__ bq,
                                                short* __restrict__ qp) {
    __shared__ short Xl[128 * 256]; // [px][c], rows 512B = 32 granules, swizzled
    int bi = blockIdx.x;            // 512 = 4b * 128tiles
    int b = bi >> 7, tile = bi & 127;
    long px0 = (long)tile * 128;
    int t = threadIdx.x, l = t & 63, w = t >> 6;
    int low = l & 15, ql = l >> 4;
#pragma unroll
    for (int i = 0; i < 16; ++i) {
        int g = i * 256 + t;        // 4096 granules
        int px = g >> 5, lg = g & 31;
        short8 v = *(const short8*)(xn + (((long)(b << 14)) + px0 + px) * 256 + lg * 8);
        *(short8*)(Xl + px * 256 + ((lg ^ (px & 7)) * 8)) = v;
    }
    __syncthreads();

    f32x4 acc[16][2];
#pragma unroll
    for (int mt = 0; mt < 16; ++mt) {
        acc[mt][0] = (f32x4){0.f, 0.f, 0.f, 0.f};
        acc[mt][1] = (f32x4){0.f, 0.f, 0.f, 0.f};
    }
#pragma unroll
    for (int kstep = 0; kstep < 8; ++kstep) {
        short8 bf[2];
#pragma unroll
        for (int nt = 0; nt < 2; ++nt) {
            int px = w * 32 + nt * 16 + low;
            int lg = kstep * 4 + ql;
            bf[nt] = *(const short8*)(Xl + px * 256 + ((lg ^ (px & 7)) * 8));
        }
#pragma unroll
        for (int mt = 0; mt < 16; ++mt) {
            short8 af = *(const short8*)(wqp + (mt * 16 + low) * 256 + kstep * 32 + ql * 8);
#pragma unroll
            for (int nt = 0; nt < 2; ++nt)
                acc[mt][nt] = mfma_k32(af, bf[nt], acc[mt][nt]);
        }
    }
    // epilogue: D row(oc)=mt*16+ql*4+r, col(px)=w*32+nt*16+low.
    // Transpose via LDS (Xl dead): Tb[px 128][h 8][c 32] f16, pitch 256 shorts
    // (exactly Xl's 32768 shorts). 16B-granule index XOR-swizzled with (px&7)
    // on both sides to break the 512B-row bank alignment.
    __syncthreads();
    short* Tb = Xl;
#pragma unroll
    for (int mt = 0; mt < 16; ++mt)
#pragma unroll
        for (int nt = 0; nt < 2; ++nt) {
            int pxl = w * 32 + nt * 16 + low;
            int oc0 = mt * 16 + ql * 4;
#pragma unroll
            for (int r = 0; r < 4; ++r) {
                int oc = oc0 + r;
                int h8 = oc & 7, cc = oc >> 3;
                int gi = h8 * 4 + (cc >> 3);      // 16B granule 0..31 within row
                Tb[pxl * 256 + ((gi ^ (pxl & 7)) * 8) + (cc & 7)] =
                    f2h(acc[mt][nt][r] + bq[oc]);
            }
        }
    __syncthreads();
#pragma unroll
    for (int i = 0; i < 16; ++i) {
        int g = i * 256 + t;            // 4096 chunks of 16B
        int pxl = g >> 5, g16 = g & 31; // g16 = hh*4 + oct
        int hh = g16 >> 2, oct = g16 & 3;
        short8 v = *(const short8*)(Tb + pxl * 256 + ((g16 ^ (pxl & 7)) * 8));
        *(short8*)(qp + (((long)(b * 8 + hh) * 16384) + px0 + pxl) * 32 + oct * 8) = v;
    }
}

// ---------------- fused attention (v3) ----------------
// grid 4096 = 4b * 8h * 128 tiles of 128px; block 256 thr = 4 waves x 32 px.
// K fragments hoisted to registers (loaded once, coalesced, reused both nt).
// V staged in LDS [c 32][key 256] pitch 264 shorts (16B-aligned rows).
// q read as one 16B vector per lane per nt from [b][h][px][c].
// QK^T swapped: D[key][px]; P feeds PV directly as 16x16x16 B-operand.
__global__ __launch_bounds__(256) void k_attn(const short* __restrict__ qp,
                                              const short* __restrict__ kp,
                                              const short* __restrict__ vp,
                                              float* __restrict__ out) {
    __shared__ short Vl[32 * 264];   // 16.9 KB
    int bi = blockIdx.x;
    int tile = bi & 127, h = (bi >> 7) & 7, b = bi >> 10;
    int bh = b * 8 + h;
    long px0 = (long)tile * 128;
    int t = threadIdx.x, l = t & 63, w = t >> 6;
    int low = l & 15, q = l >> 4;

    const short* kbase = kp + (long)bh * 8192;    // [key 256][c 32]
    const short* vbase = vp + (long)bh * 8192;    // [c 32][key 256]
    const short* qbase = qp + (long)bh * 16384 * 32;  // [px][c 32]

    // stage V -> LDS (coalesced 16B)
#pragma unroll
    for (int i = 0; i < 4; ++i) {
        int g = i * 256 + t;          // 1024 = 32c * 32 chunks
        int c = g >> 5, k8 = g & 31;
        short8 v = *(const short8*)(vbase + c * 256 + k8 * 8);
        *(short8*)(Vl + c * 264 + k8 * 8) = v;
    }
    // K fragments -> registers (coalesced 1KB/wave per mt, L1/L2 hot)
    short8 kf[16];
#pragma unroll
    for (int mt = 0; mt < 16; ++mt)
        kf[mt] = *(const short8*)(kbase + (mt * 16 + low) * 32 + q * 8);
    __syncthreads();

#pragma unroll 1
    for (int nt = 0; nt < 2; ++nt) {
        long px = px0 + w * 32 + nt * 16 + low;
        // q B-frag: 16B contiguous (k = c = q*8+j)
        short8 bq2 = *(const short8*)(qbase + px * 32 + q * 8);

        // QK^T: d[mt] holds keys mt*16 + q*4 + r, col = px  (no loads inside)
        f32x4 d[16];
#pragma unroll
        for (int mt = 0; mt < 16; ++mt) d[mt] = (f32x4){0.f, 0.f, 0.f, 0.f};
        __builtin_amdgcn_s_setprio(1);
#pragma unroll
        for (int mt = 0; mt < 16; ++mt) d[mt] = mfma_k32(kf[mt], bq2, d[mt]);
        __builtin_amdgcn_s_setprio(0);

        // softmax over 256 keys: 64 lane-local + xor over lane bits 4,5
        float m = -1e30f;
#pragma unroll
        for (int mt = 0; mt < 16; ++mt)
#pragma unroll
            for (int r = 0; r < 4; ++r) m = fmaxf(m, d[mt][r]);
        m = fmaxf(m, __shfl_xor(m, 16));
        m = fmaxf(m, __shfl_xor(m, 32));
        float s = 0.f;
#pragma unroll
        for (int mt = 0; mt < 16; ++mt)
#pragma unroll
            for (int r = 0; r < 4; ++r) {
                float p = __expf(d[mt][r] - m);
                d[mt][r] = p;
                s += p;
            }
        s += __shfl_xor(s, 16);
        s += __shfl_xor(s, 32);
        float inv = 1.0f / s;

        // PV: o2[ct] = sum_kc V^T[c][16keys] x P[16keys][px]  (16x16x16)
        f32x4 o2[2];
        o2[0] = (f32x4){0.f, 0.f, 0.f, 0.f};
        o2[1] = (f32x4){0.f, 0.f, 0.f, 0.f};
#pragma unroll
        for (int kc = 0; kc < 16; ++kc) {
            uint2v uu;
            uu[0] = __builtin_bit_cast(unsigned int,
                      __builtin_amdgcn_cvt_pkrtz(d[kc][0], d[kc][1]));
            uu[1] = __builtin_bit_cast(unsigned int,
                      __builtin_amdgcn_cvt_pkrtz(d[kc][2], d[kc][3]));
            half4 pb = __builtin_bit_cast(half4, uu);
#pragma unroll
            for (int ct = 0; ct < 2; ++ct) {
                half4 av = __builtin_bit_cast(half4,
                    *(const sh4*)(Vl + (ct * 16 + low) * 264 + kc * 16 + q * 4));
                o2[ct] = mfma_k16(av, pb, o2[ct]);
            }
        }
        // write out [b][c*8+h][px] fp32; D row=c=ct*16+q*4+r, col=px
#pragma unroll
        for (int ct = 0; ct < 2; ++ct)
#pragma unroll
            for (int r = 0; r < 4; ++r) {
                int c = ct * 16 + q * 4 + r;
                out[(((long)(b * 256 + c * 8 + h)) << 14) + px] = o2[ct][r] * inv;
            }
    }
}

// ---------------- launch ----------------
extern "C" void kernel_launch(void* const* d_in, const int* in_sizes, int n_in,
                              void* d_out, int out_size, void* d_ws, size_t ws_size,
                              hipStream_t stream) {
    const float* x  = (const float*)d_in[0];
    const float* Wq = (const float*)d_in[1];
    const float* bq = (const float*)d_in[2];
    const float* Wk = (const float*)d_in[3];
    const float* bk = (const float*)d_in[4];
    const float* Wv = (const float*)d_in[5];
    const float* bv = (const float*)d_in[6];
    float* out = (float*)d_out;

    char* ws = (char*)d_ws;
    const size_t OFF_XN = 0;             // 33,554,432  x NHWC f16
    const size_t OFF_Q  = 33554432;      // 33,554,432  q [b][h][px][c] f16
    const size_t OFF_WP = 67108864;      // 16,777,216  w_pack [512][16384] f16
    const size_t OFF_WQ = 83886080;      //    131,072  wq f16
    const size_t OFF_KP = 84017152;      //    524,288  k_pack f16
    const size_t OFF_VP = 84541440;      //    524,288  v_pack f16
    const size_t OFF_PT = 85065728;      // 33,554,432  partials fp32 [16][1024][512]
    const size_t NEEDED = 118620160;
    if (ws_size < NEEDED) return;        // fail loudly via validation

    short* xn  = (short*)(ws + OFF_XN);
    short* qp  = (short*)(ws + OFF_Q);
    short* wp  = (short*)(ws + OFF_WP);
    short* wqp = (short*)(ws + OFF_WQ);
    short* kp  = (short*)(ws + OFF_KP);
    short* vp  = (short*)(ws + OFF_VP);
    float* part= (float*)(ws + OFF_PT);

    k_pack_x <<<dim3(4096), dim3(256), 0, stream>>>(x, xn);
    k_pack_w <<<dim3(2048), dim3(256), 0, stream>>>(Wk, Wv, wp);
    k_pack_wq<<<dim3(256),  dim3(256), 0, stream>>>(Wq, wqp);
    k_kv_gemm<<<dim3(256),  dim3(512), 0, stream>>>(xn, wp, part);
    k_kv_fin <<<dim3(2048), dim3(256), 0, stream>>>(part, bk, bv, kp, vp);
    k_q_gemm <<<dim3(512),  dim3(256), 0, stream>>>(xn, wqp, bq, qp);
    k_attn   <<<dim3(4096), dim3(256), 0, stream>>>(qp, kp, vp, out);
}

// Round 7
// 212.648 us; speedup vs baseline: 1.2621x; 1.0219x over previous
//
#include <hip/hip_runtime.h>
#include <stdint.h>

// ---------------- types & helpers ----------------
typedef short sh4 __attribute__((ext_vector_type(4)));
typedef short short8 __attribute__((ext_vector_type(8)));
typedef float f32x4 __attribute__((ext_vector_type(4)));
typedef _Float16 half4 __attribute__((ext_vector_type(4)));
typedef _Float16 half8 __attribute__((ext_vector_type(8)));
typedef unsigned int uint2v __attribute__((ext_vector_type(2)));

__device__ __forceinline__ short f2h(float f) {
    _Float16 h = (_Float16)f;
    return __builtin_bit_cast(short, h);
}

__device__ __forceinline__ f32x4 mfma_k32(short8 a, short8 b, f32x4 c) {
    return __builtin_amdgcn_mfma_f32_16x16x32_f16(
        __builtin_bit_cast(half8, a), __builtin_bit_cast(half8, b), c, 0, 0, 0);
}
__device__ __forceinline__ f32x4 mfma_k16(half4 a, half4 b, f32x4 c) {
    return __builtin_amdgcn_mfma_f32_16x16x16f16(a, b, c, 0, 0, 0);
}

// Problem constants: B=4, C=256, H=W=128 (PX=16384), inner=256, heads=8, c/head=32,
// patch=8 -> keys=256, conv K-dim = 256*64 = 16384.
// NOTE: logit std ~4.6, max over row can reach ~25 -> per-row max subtraction is
// REQUIRED before exp if P is packed to f16 (learned round 6).

// ---------------- pack kernels: 64x64 fp32 tile transpose -> f16 ----------------
__device__ __forceinline__ void transpose64(const float* __restrict__ src,
                                            short* __restrict__ dst,
                                            int srcSlowStride, int dstRowStride) {
    __shared__ float tile[64][65];
    const int t = threadIdx.x;
#pragma unroll
    for (int i = 0; i < 16; ++i) {
        int idx = i * 256 + t;
        int fast = idx & 63, slow = idx >> 6;
        tile[slow][fast] = src[(long)slow * srcSlowStride + fast];
    }
    __syncthreads();
#pragma unroll
    for (int i = 0; i < 2; ++i) {
        int ch = i * 256 + t;
        int fast = ch >> 3, sg = ch & 7;
        short8 v;
#pragma unroll
        for (int j = 0; j < 8; ++j) v[j] = f2h(tile[sg * 8 + j][fast]);
        *(short8*)(dst + (long)fast * dstRowStride + sg * 8) = v;
    }
}

// x: [4][256][16384] fp32 (NCHW) -> xn: [4][16384][256] f16 (NHWC)
__global__ __launch_bounds__(256) void k_pack_x(const float* __restrict__ x,
                                                short* __restrict__ xn) {
    int bi = blockIdx.x;                 // 4096 = 4b * 256pxt * 4ct
    int ct = bi & 3, pxt = (bi >> 2) & 255, b = bi >> 10;
    const float* src = x + (((long)(b * 256 + ct * 64)) << 14) + (long)pxt * 64;
    short* dst = xn + (((long)(b << 14) + pxt * 64) * 256) + ct * 64;
    transpose64(src, dst, 16384, 256);
}

// Wk/Wv: [256][256][64] fp32 -> wp: [512][64][256] f16 (oc<256: k, else v), K order (dydx, c)
__global__ __launch_bounds__(256) void k_pack_w(const float* __restrict__ wk,
                                                const float* __restrict__ wv,
                                                short* __restrict__ wp) {
    int bi = blockIdx.x;                 // 2048 = 512oc * 4ct
    int ct = bi & 3, oc = bi >> 2;
    const float* base = (oc < 256) ? (wk + (long)oc * 16384) : (wv + (long)(oc - 256) * 16384);
    const float* src = base + ct * 4096; // + c0*64
    short* dst = wp + (long)oc * 16384 + ct * 64;
    transpose64(src, dst, 64, 256);
}

// Wq: [256][256] fp32 -> f16 (layout preserved: [oc][c])
__global__ __launch_bounds__(256) void k_pack_wq(const float* __restrict__ wq,
                                                 short* __restrict__ wqp) {
    int i = blockIdx.x * 256 + threadIdx.x; // grid 256 -> 65536
    wqp[i] = f2h(wq[i]);
}

// ---------------- K/V conv as GEMM (128x128 tile, 4 waves, K-split 8) ----
// C[patch 1024][oc 512] = A[patch][k 16384] * B[k][oc]
// grid 256 = 8kc * 8pm * 4nb; block 256 thr; per block Kchunk 2048 (32 x BK=64)
__global__ __launch_bounds__(256) void k_kv_gemm(const short* __restrict__ xn,
                                                 const short* __restrict__ wp,
                                                 float* __restrict__ part) {
    __shared__ short Al[128 * 64]; // rows 128B = 8 granules, swizzled
    __shared__ short Bl[128 * 64];
    int bid = blockIdx.x;                       // 256
    int wg = (bid & 7) * 32 + (bid >> 3);       // XCD-contiguous swizzle (256 = 8*32)
    int nb = wg & 3, pm = (wg >> 2) & 7, kc = wg >> 5;
    int t = threadIdx.x, l = t & 63, w = t >> 6;
    int wm = w >> 1, wn = w & 1;
    int low = l & 15, q = l >> 4;

    f32x4 acc[4][4];
#pragma unroll
    for (int mt = 0; mt < 4; ++mt)
#pragma unroll
        for (int nt = 0; nt < 4; ++nt) acc[mt][nt] = (f32x4){0.f, 0.f, 0.f, 0.f};

    for (int kk = 0; kk < 32; ++kk) {
        short8 va[4], vb[4];
#pragma unroll
        for (int i = 0; i < 4; ++i) {           // A: 1024 granules
            int g = i * 256 + t;
            int row = g >> 3, lg = g & 7;
            int patch = pm * 128 + row;
            int kg = kc * 2048 + kk * 64 + lg * 8;
            int dydx = kg >> 8, cc = kg & 255;
            int bb = patch >> 8, pid = patch & 255;
            int ph = pid >> 4, pw = pid & 15;
            int px = (ph * 8 + (dydx >> 3)) * 128 + pw * 8 + (dydx & 7);
            va[i] = *(const short8*)(xn + ((long)(bb << 14) + px) * 256 + cc);
        }
#pragma unroll
        for (int i = 0; i < 4; ++i) {           // B: 1024 granules
            int g = i * 256 + t;
            int row = g >> 3, lg = g & 7;
            int oc = nb * 128 + row;
            int kg = kc * 2048 + kk * 64 + lg * 8;
            vb[i] = *(const short8*)(wp + (long)oc * 16384 + kg);
        }
#pragma unroll
        for (int i = 0; i < 4; ++i) {
            int g = i * 256 + t;
            int row = g >> 3, lg = g & 7;
            *(short8*)(Al + row * 64 + ((lg ^ (row & 7)) * 8)) = va[i];
        }
#pragma unroll
        for (int i = 0; i < 4; ++i) {
            int g = i * 256 + t;
            int row = g >> 3, lg = g & 7;
            *(short8*)(Bl + row * 64 + ((lg ^ (row & 7)) * 8)) = vb[i];
        }
        __syncthreads();
#pragma unroll
        for (int ks = 0; ks < 2; ++ks) {
            short8 af[4], bf[4];
#pragma unroll
            for (int mt = 0; mt < 4; ++mt) {
                int row = wm * 64 + mt * 16 + low;
                int lg = ks * 4 + q;
                af[mt] = *(const short8*)(Al + row * 64 + ((lg ^ (row & 7)) * 8));
            }
#pragma unroll
            for (int nt = 0; nt < 4; ++nt) {
                int row = wn * 64 + nt * 16 + low;
                int lg = ks * 4 + q;
                bf[nt] = *(const short8*)(Bl + row * 64 + ((lg ^ (row & 7)) * 8));
            }
#pragma unroll
            for (int mt = 0; mt < 4; ++mt)
#pragma unroll
                for (int nt = 0; nt < 4; ++nt)
                    acc[mt][nt] = mfma_k32(af[mt], bf[nt], acc[mt][nt]);
        }
        __syncthreads();
    }
    // D: row(patch) = q*4+r (+16mt+64wm+128pm), col(oc) = low (+16nt+64wn+128nb)
#pragma unroll
    for (int mt = 0; mt < 4; ++mt) {
        int patch = pm * 128 + wm * 64 + mt * 16 + q * 4;
#pragma unroll
        for (int nt = 0; nt < 4; ++nt) {
            int oc = nb * 128 + wn * 64 + nt * 16 + low;
#pragma unroll
            for (int r = 0; r < 4; ++r)
                part[((long)kc * 1024 + patch + r) * 512 + oc] = acc[mt][nt][r];
        }
    }
}

// reduce partials, add bias, pack k -> [b][h][key][c], v -> [b][h][c][key] (f16)
__global__ __launch_bounds__(256) void k_kv_fin(const float* __restrict__ part,
                                                const float* __restrict__ bk,
                                                const float* __restrict__ bv,
                                                short* __restrict__ kp,
                                                short* __restrict__ vp) {
    int idx = blockIdx.x * 256 + threadIdx.x;   // 524288 = 1024patch * 512oc
    int oc = idx & 511, patch = idx >> 9;
    float s = 0.f;
#pragma unroll
    for (int kc = 0; kc < 8; ++kc) s += part[(long)kc * 524288 + idx];
    int b = patch >> 8, key = patch & 255;
    if (oc < 256) {
        s += bk[oc];
        kp[(((long)(b * 8 + (oc & 7)) * 256) + key) * 32 + (oc >> 3)] = f2h(s);
    } else {
        int o = oc - 256;
        s += bv[o];
        vp[(((long)(b * 8 + (o & 7)) * 32) + (o >> 3)) * 256 + key] = f2h(s);
    }
}

// ---------------- Q conv (1x1) as GEMM ----------------
// MFMA computes D[oc 256][px 128]; epilogue transposes through LDS so q is
// stored as [b][h 8][px 16384][c 32] f16 (attention reads 16B per lane).
__global__ __launch_bounds__(256) void k_q_gemm(const short* __restrict__ xn,
                                                const short* __restrict__ wqp,
                                                const float* __restrict__ bq,
                                                short* __restrict__ qp) {
    __shared__ short Xl[128 * 256]; // [px][c], rows 512B = 32 granules, swizzled
    int bi = blockIdx.x;            // 512 = 4b * 128tiles
    int b = bi >> 7, tile = bi & 127;
    long px0 = (long)tile * 128;
    int t = threadIdx.x, l = t & 63, w = t >> 6;
    int low = l & 15, ql = l >> 4;
#pragma unroll
    for (int i = 0; i < 16; ++i) {
        int g = i * 256 + t;        // 4096 granules
        int px = g >> 5, lg = g & 31;
        short8 v = *(const short8*)(xn + (((long)(b << 14)) + px0 + px) * 256 + lg * 8);
        *(short8*)(Xl + px * 256 + ((lg ^ (px & 7)) * 8)) = v;
    }
    __syncthreads();

    f32x4 acc[16][2];
#pragma unroll
    for (int mt = 0; mt < 16; ++mt) {
        acc[mt][0] = (f32x4){0.f, 0.f, 0.f, 0.f};
        acc[mt][1] = (f32x4){0.f, 0.f, 0.f, 0.f};
    }
#pragma unroll
    for (int kstep = 0; kstep < 8; ++kstep) {
        short8 bf[2];
#pragma unroll
        for (int nt = 0; nt < 2; ++nt) {
            int px = w * 32 + nt * 16 + low;
            int lg = kstep * 4 + ql;
            bf[nt] = *(const short8*)(Xl + px * 256 + ((lg ^ (px & 7)) * 8));
        }
#pragma unroll
        for (int mt = 0; mt < 16; ++mt) {
            short8 af = *(const short8*)(wqp + (mt * 16 + low) * 256 + kstep * 32 + ql * 8);
#pragma unroll
            for (int nt = 0; nt < 2; ++nt)
                acc[mt][nt] = mfma_k32(af, bf[nt], acc[mt][nt]);
        }
    }
    // epilogue: D row(oc)=mt*16+ql*4+r, col(px)=w*32+nt*16+low.
    // Transpose via LDS (Xl dead): Tb[px 128][h 8][c 32] f16, pitch 256 shorts,
    // 16B-granule index XOR-swizzled with (px&7) on both sides.
    __syncthreads();
    short* Tb = Xl;
#pragma unroll
    for (int mt = 0; mt < 16; ++mt)
#pragma unroll
        for (int nt = 0; nt < 2; ++nt) {
            int pxl = w * 32 + nt * 16 + low;
            int oc0 = mt * 16 + ql * 4;
#pragma unroll
            for (int r = 0; r < 4; ++r) {
                int oc = oc0 + r;
                int h8 = oc & 7, cc = oc >> 3;
                int gi = h8 * 4 + (cc >> 3);      // 16B granule 0..31 within row
                Tb[pxl * 256 + ((gi ^ (pxl & 7)) * 8) + (cc & 7)] =
                    f2h(acc[mt][nt][r] + bq[oc]);
            }
        }
    __syncthreads();
#pragma unroll
    for (int i = 0; i < 16; ++i) {
        int g = i * 256 + t;            // 4096 chunks of 16B
        int pxl = g >> 5, g16 = g & 31; // g16 = hh*4 + oct
        int hh = g16 >> 2, oct = g16 & 3;
        short8 v = *(const short8*)(Tb + pxl * 256 + ((g16 ^ (pxl & 7)) * 8));
        *(short8*)(qp + (((long)(b * 8 + hh) * 16384) + px0 + pxl) * 32 + oct * 8) = v;
    }
}

// ---------------- fused attention (v5: two-pass QK^T, lean VGPR) ----------------
// grid 4096 = 4b * 8h * 128 tiles of 128px; block 256 thr = 4 waves x 32 px.
// K staged in LDS [key][c]; V staged in LDS [c][key] pitch 264.
// Pass 1: 16 MFMAs, fold fmax (no d[16] array) -> row max via 2 shfl.
// Pass 2: recompute MFMAs, fused exp/pack/sum -> pk[16] (32 VGPR).
// P feeds PV directly as 16x16x16 B-operand; V A-frags from LDS.
__global__ __launch_bounds__(256) void k_attn(const short* __restrict__ qp,
                                              const short* __restrict__ kp,
                                              const short* __restrict__ vp,
                                              float* __restrict__ out) {
    __shared__ short Kl[256 * 32];   // 16 KB, straight copy of kp tile
    __shared__ short Vl[32 * 264];   // 16.9 KB
    int bi = blockIdx.x;
    int tile = bi & 127, h = (bi >> 7) & 7, b = bi >> 10;
    int bh = b * 8 + h;
    long px0 = (long)tile * 128;
    int t = threadIdx.x, l = t & 63, w = t >> 6;
    int low = l & 15, q = l >> 4;

    const short* kbase = kp + (long)bh * 8192;    // [key 256][c 32]
    const short* vbase = vp + (long)bh * 8192;    // [c 32][key 256]
    const short* qbase = qp + (long)bh * 16384 * 32;  // [px][c 32]

    // stage K -> LDS (straight 16KB copy, coalesced)
#pragma unroll
    for (int i = 0; i < 4; ++i) {
        int g = i * 256 + t;
        *(short8*)(Kl + g * 8) = *(const short8*)(kbase + g * 8);
    }
    // stage V -> LDS (pitch 264)
#pragma unroll
    for (int i = 0; i < 4; ++i) {
        int g = i * 256 + t;
        int c = g >> 5, k8 = g & 31;
        *(short8*)(Vl + c * 264 + k8 * 8) = *(const short8*)(vbase + c * 256 + k8 * 8);
    }
    // both q B-frags upfront (16B contiguous each; k = c = q*8+j)
    short8 bq2[2];
#pragma unroll
    for (int nt = 0; nt < 2; ++nt) {
        long px = px0 + w * 32 + nt * 16 + low;
        bq2[nt] = *(const short8*)(qbase + px * 32 + q * 8);
    }
    __syncthreads();

#pragma unroll 1
    for (int nt = 0; nt < 2; ++nt) {
        // pass 1: row max (d dies each iteration -> no 64-VGPR array)
        float m = -1e30f;
#pragma unroll
        for (int mt = 0; mt < 16; ++mt) {
            short8 ak = *(const short8*)(Kl + (mt * 16 + low) * 32 + q * 8);
            f32x4 d = mfma_k32(ak, bq2[nt], (f32x4){0.f, 0.f, 0.f, 0.f});
            m = fmaxf(m, fmaxf(fmaxf(d[0], d[1]), fmaxf(d[2], d[3])));
        }
        m = fmaxf(m, __shfl_xor(m, 16));
        m = fmaxf(m, __shfl_xor(m, 32));

        // pass 2: recompute, exp, pack, sum
        float s = 0.f;
        uint2v pk[16];
#pragma unroll
        for (int mt = 0; mt < 16; ++mt) {
            short8 ak = *(const short8*)(Kl + (mt * 16 + low) * 32 + q * 8);
            f32x4 d = mfma_k32(ak, bq2[nt], (f32x4){0.f, 0.f, 0.f, 0.f});
            float p0 = __expf(d[0] - m);
            float p1 = __expf(d[1] - m);
            float p2 = __expf(d[2] - m);
            float p3 = __expf(d[3] - m);
            s += (p0 + p1) + (p2 + p3);
            pk[mt][0] = __builtin_bit_cast(unsigned int,
                          __builtin_amdgcn_cvt_pkrtz(p0, p1));
            pk[mt][1] = __builtin_bit_cast(unsigned int,
                          __builtin_amdgcn_cvt_pkrtz(p2, p3));
        }
        s += __shfl_xor(s, 16);
        s += __shfl_xor(s, 32);
        float inv = 1.0f / s;

        // PV: o2[ct] = sum_kc V^T[c][16keys] x P[16keys][px]  (16x16x16)
        f32x4 o2[2];
        o2[0] = (f32x4){0.f, 0.f, 0.f, 0.f};
        o2[1] = (f32x4){0.f, 0.f, 0.f, 0.f};
#pragma unroll
        for (int kc = 0; kc < 16; ++kc) {
            half4 pb = __builtin_bit_cast(half4, pk[kc]);
#pragma unroll
            for (int ct = 0; ct < 2; ++ct) {
                half4 av = __builtin_bit_cast(half4,
                    *(const sh4*)(Vl + (ct * 16 + low) * 264 + kc * 16 + q * 4));
                o2[ct] = mfma_k16(av, pb, o2[ct]);
            }
        }
        // write out [b][c*8+h][px] fp32; D row=c=ct*16+q*4+r, col=px
        long px = px0 + w * 32 + nt * 16 + low;
#pragma unroll
        for (int ct = 0; ct < 2; ++ct)
#pragma unroll
            for (int r = 0; r < 4; ++r) {
                int c = ct * 16 + q * 4 + r;
                out[(((long)(b * 256 + c * 8 + h)) << 14) + px] = o2[ct][r] * inv;
            }
    }
}

// ---------------- launch ----------------
extern "C" void kernel_launch(void* const* d_in, const int* in_sizes, int n_in,
                              void* d_out, int out_size, void* d_ws, size_t ws_size,
                              hipStream_t stream) {
    const float* x  = (const float*)d_in[0];
    const float* Wq = (const float*)d_in[1];
    const float* bq = (const float*)d_in[2];
    const float* Wk = (const float*)d_in[3];
    const float* bk = (const float*)d_in[4];
    const float* Wv = (const float*)d_in[5];
    const float* bv = (const float*)d_in[6];
    float* out = (float*)d_out;

    char* ws = (char*)d_ws;
    const size_t OFF_XN = 0;             // 33,554,432  x NHWC f16
    const size_t OFF_Q  = 33554432;      // 33,554,432  q [b][h][px][c] f16
    const size_t OFF_WP = 67108864;      // 16,777,216  w_pack [512][16384] f16
    const size_t OFF_WQ = 83886080;      //    131,072  wq f16
    const size_t OFF_KP = 84017152;      //    524,288  k_pack f16
    const size_t OFF_VP = 84541440;      //    524,288  v_pack f16
    const size_t OFF_PT = 85065728;      // 16,777,216  partials fp32 [8][1024][512]
    const size_t NEEDED = 118620160;
    if (ws_size < NEEDED) return;        // fail loudly via validation

    short* xn  = (short*)(ws + OFF_XN);
    short* qp  = (short*)(ws + OFF_Q);
    short* wp  = (short*)(ws + OFF_WP);
    short* wqp = (short*)(ws + OFF_WQ);
    short* kp  = (short*)(ws + OFF_KP);
    short* vp  = (short*)(ws + OFF_VP);
    float* part= (float*)(ws + OFF_PT);

    k_pack_x <<<dim3(4096), dim3(256), 0, stream>>>(x, xn);
    k_pack_w <<<dim3(2048), dim3(256), 0, stream>>>(Wk, Wv, wp);
    k_pack_wq<<<dim3(256),  dim3(256), 0, stream>>>(Wq, wqp);
    k_kv_gemm<<<dim3(256),  dim3(256), 0, stream>>>(xn, wp, part);
    k_kv_fin <<<dim3(2048), dim3(256), 0, stream>>>(part, bk, bv, kp, vp);
    k_q_gemm <<<dim3(512),  dim3(256), 0, stream>>>(xn, wqp, bq, qp);
    k_attn   <<<dim3(4096), dim3(256), 0, stream>>>(qp, kp, vp, out);
}

// Round 8
// 178.115 us; speedup vs baseline: 1.5067x; 1.1939x over previous
//
#include <hip/hip_runtime.h>
#include <stdint.h>

// ---------------- types & helpers ----------------
typedef short sh4 __attribute__((ext_vector_type(4)));
typedef short short8 __attribute__((ext_vector_type(8)));
typedef float f32x4 __attribute__((ext_vector_type(4)));
typedef _Float16 half4 __attribute__((ext_vector_type(4)));
typedef _Float16 half8 __attribute__((ext_vector_type(8)));
typedef unsigned int uint2v __attribute__((ext_vector_type(2)));

__device__ __forceinline__ short f2h(float f) {
    _Float16 h = (_Float16)f;
    return __builtin_bit_cast(short, h);
}

__device__ __forceinline__ f32x4 mfma_k32(short8 a, short8 b, f32x4 c) {
    return __builtin_amdgcn_mfma_f32_16x16x32_f16(
        __builtin_bit_cast(half8, a), __builtin_bit_cast(half8, b), c, 0, 0, 0);
}
__device__ __forceinline__ f32x4 mfma_k16(half4 a, half4 b, f32x4 c) {
    return __builtin_amdgcn_mfma_f32_16x16x16f16(a, b, c, 0, 0, 0);
}

// Problem constants: B=4, C=256, H=W=128 (PX=16384), inner=256, heads=8, c/head=32,
// patch=8 -> keys=256, conv K-dim = 256*64 = 16384.
// NOTE: logit std ~4.6, max over row can reach ~25 -> per-row max subtraction is
// REQUIRED before exp if P is packed to f16 (learned round 6).

// ---------------- pack kernels: 64x64 fp32 tile transpose -> f16 ----------------
__device__ __forceinline__ void transpose64(const float* __restrict__ src,
                                            short* __restrict__ dst,
                                            int srcSlowStride, int dstRowStride) {
    __shared__ float tile[64][65];
    const int t = threadIdx.x;
#pragma unroll
    for (int i = 0; i < 16; ++i) {
        int idx = i * 256 + t;
        int fast = idx & 63, slow = idx >> 6;
        tile[slow][fast] = src[(long)slow * srcSlowStride + fast];
    }
    __syncthreads();
#pragma unroll
    for (int i = 0; i < 2; ++i) {
        int ch = i * 256 + t;
        int fast = ch >> 3, sg = ch & 7;
        short8 v;
#pragma unroll
        for (int j = 0; j < 8; ++j) v[j] = f2h(tile[sg * 8 + j][fast]);
        *(short8*)(dst + (long)fast * dstRowStride + sg * 8) = v;
    }
}

// x: [4][256][16384] fp32 (NCHW) -> xn: [4][16384][256] f16 (NHWC)
__global__ __launch_bounds__(256) void k_pack_x(const float* __restrict__ x,
                                                short* __restrict__ xn) {
    int bi = blockIdx.x;                 // 4096 = 4b * 256pxt * 4ct
    int ct = bi & 3, pxt = (bi >> 2) & 255, b = bi >> 10;
    const float* src = x + (((long)(b * 256 + ct * 64)) << 14) + (long)pxt * 64;
    short* dst = xn + (((long)(b << 14) + pxt * 64) * 256) + ct * 64;
    transpose64(src, dst, 16384, 256);
}

// Wk/Wv: [256][256][64] fp32 -> wp: [512][64][256] f16 (oc<256: k, else v), K order (dydx, c)
__global__ __launch_bounds__(256) void k_pack_w(const float* __restrict__ wk,
                                                const float* __restrict__ wv,
                                                short* __restrict__ wp) {
    int bi = blockIdx.x;                 // 2048 = 512oc * 4ct
    int ct = bi & 3, oc = bi >> 2;
    const float* base = (oc < 256) ? (wk + (long)oc * 16384) : (wv + (long)(oc - 256) * 16384);
    const float* src = base + ct * 4096; // + c0*64
    short* dst = wp + (long)oc * 16384 + ct * 64;
    transpose64(src, dst, 64, 256);
}

// Wq: [256][256] fp32 -> f16 (layout preserved: [oc][c])
__global__ __launch_bounds__(256) void k_pack_wq(const float* __restrict__ wq,
                                                 short* __restrict__ wqp) {
    int i = blockIdx.x * 256 + threadIdx.x; // grid 256 -> 65536
    wqp[i] = f2h(wq[i]);
}

// ---------------- K/V conv as GEMM (128x128 tile, 4 waves, K-split 8) ----
// C[patch 1024][oc 512] = A[patch][k 16384] * B[k][oc]
// grid 256 = 8kc * 8pm * 4nb; block 256 thr; per block Kchunk 2048 (32 x BK=64)
__global__ __launch_bounds__(256) void k_kv_gemm(const short* __restrict__ xn,
                                                 const short* __restrict__ wp,
                                                 float* __restrict__ part) {
    __shared__ short Al[128 * 64]; // rows 128B = 8 granules, swizzled
    __shared__ short Bl[128 * 64];
    int bid = blockIdx.x;                       // 256
    int wg = (bid & 7) * 32 + (bid >> 3);       // XCD-contiguous swizzle (256 = 8*32)
    int nb = wg & 3, pm = (wg >> 2) & 7, kc = wg >> 5;
    int t = threadIdx.x, l = t & 63, w = t >> 6;
    int wm = w >> 1, wn = w & 1;
    int low = l & 15, q = l >> 4;

    f32x4 acc[4][4];
#pragma unroll
    for (int mt = 0; mt < 4; ++mt)
#pragma unroll
        for (int nt = 0; nt < 4; ++nt) acc[mt][nt] = (f32x4){0.f, 0.f, 0.f, 0.f};

    for (int kk = 0; kk < 32; ++kk) {
        short8 va[4], vb[4];
#pragma unroll
        for (int i = 0; i < 4; ++i) {           // A: 1024 granules
            int g = i * 256 + t;
            int row = g >> 3, lg = g & 7;
            int patch = pm * 128 + row;
            int kg = kc * 2048 + kk * 64 + lg * 8;
            int dydx = kg >> 8, cc = kg & 255;
            int bb = patch >> 8, pid = patch & 255;
            int ph = pid >> 4, pw = pid & 15;
            int px = (ph * 8 + (dydx >> 3)) * 128 + pw * 8 + (dydx & 7);
            va[i] = *(const short8*)(xn + ((long)(bb << 14) + px) * 256 + cc);
        }
#pragma unroll
        for (int i = 0; i < 4; ++i) {           // B: 1024 granules
            int g = i * 256 + t;
            int row = g >> 3, lg = g & 7;
            int oc = nb * 128 + row;
            int kg = kc * 2048 + kk * 64 + lg * 8;
            vb[i] = *(const short8*)(wp + (long)oc * 16384 + kg);
        }
#pragma unroll
        for (int i = 0; i < 4; ++i) {
            int g = i * 256 + t;
            int row = g >> 3, lg = g & 7;
            *(short8*)(Al + row * 64 + ((lg ^ (row & 7)) * 8)) = va[i];
        }
#pragma unroll
        for (int i = 0; i < 4; ++i) {
            int g = i * 256 + t;
            int row = g >> 3, lg = g & 7;
            *(short8*)(Bl + row * 64 + ((lg ^ (row & 7)) * 8)) = vb[i];
        }
        __syncthreads();
#pragma unroll
        for (int ks = 0; ks < 2; ++ks) {
            short8 af[4], bf[4];
#pragma unroll
            for (int mt = 0; mt < 4; ++mt) {
                int row = wm * 64 + mt * 16 + low;
                int lg = ks * 4 + q;
                af[mt] = *(const short8*)(Al + row * 64 + ((lg ^ (row & 7)) * 8));
            }
#pragma unroll
            for (int nt = 0; nt < 4; ++nt) {
                int row = wn * 64 + nt * 16 + low;
                int lg = ks * 4 + q;
                bf[nt] = *(const short8*)(Bl + row * 64 + ((lg ^ (row & 7)) * 8));
            }
#pragma unroll
            for (int mt = 0; mt < 4; ++mt)
#pragma unroll
                for (int nt = 0; nt < 4; ++nt)
                    acc[mt][nt] = mfma_k32(af[mt], bf[nt], acc[mt][nt]);
        }
        __syncthreads();
    }
    // D: row(patch) = q*4+r (+16mt+64wm+128pm), col(oc) = low (+16nt+64wn+128nb)
#pragma unroll
    for (int mt = 0; mt < 4; ++mt) {
        int patch = pm * 128 + wm * 64 + mt * 16 + q * 4;
#pragma unroll
        for (int nt = 0; nt < 4; ++nt) {
            int oc = nb * 128 + wn * 64 + nt * 16 + low;
#pragma unroll
            for (int r = 0; r < 4; ++r)
                part[((long)kc * 1024 + patch + r) * 512 + oc] = acc[mt][nt][r];
        }
    }
}

// reduce partials, add bias, pack k -> [b][h][key][c], v -> [b][h][c][key] (f16)
__global__ __launch_bounds__(256) void k_kv_fin(const float* __restrict__ part,
                                                const float* __restrict__ bk,
                                                const float* __restrict__ bv,
                                                short* __restrict__ kp,
                                                short* __restrict__ vp) {
    int idx = blockIdx.x * 256 + threadIdx.x;   // 524288 = 1024patch * 512oc
    int oc = idx & 511, patch = idx >> 9;
    float s = 0.f;
#pragma unroll
    for (int kc = 0; kc < 8; ++kc) s += part[(long)kc * 524288 + idx];
    int b = patch >> 8, key = patch & 255;
    if (oc < 256) {
        s += bk[oc];
        kp[(((long)(b * 8 + (oc & 7)) * 256) + key) * 32 + (oc >> 3)] = f2h(s);
    } else {
        int o = oc - 256;
        s += bv[o];
        vp[(((long)(b * 8 + (o & 7)) * 32) + (o >> 3)) * 256 + key] = f2h(s);
    }
}

// ---------------- Q conv (1x1) as GEMM (v2: no staging LDS, D[px][oc]) -------
// A-frag = xn[px][c] (16B contiguous per lane), B-frag = wqp[oc][c] (L2-hot).
// grid 1024 = 4b * 256 tiles of 64px; block 256 thr = 4 waves; wave w owns
// oc in [64w, 64w+64). LDS only for the output transpose (32KB -> 4 blocks/CU).
// q stored as [b][h 8][px 16384][c 32] f16 (attention reads 16B per lane).
__global__ __launch_bounds__(256) void k_q_gemm(const short* __restrict__ xn,
                                                const short* __restrict__ wqp,
                                                const float* __restrict__ bq,
                                                short* __restrict__ qp) {
    __shared__ short Tb[64 * 256];  // 32 KB
    int bi = blockIdx.x;            // 1024 = 4b * 256 tiles
    int b = bi >> 8, tile = bi & 255;
    long px0 = (long)tile * 64;
    int t = threadIdx.x, l = t & 63, w = t >> 6;
    int low = l & 15, q = l >> 4;

    const short* xb = xn + (((long)(b << 14)) + px0) * 256;

    float bqv[4];
#pragma unroll
    for (int nt = 0; nt < 4; ++nt) bqv[nt] = bq[w * 64 + nt * 16 + low];

    f32x4 acc[4][4];   // [mt: px][nt: oc]
#pragma unroll
    for (int mt = 0; mt < 4; ++mt)
#pragma unroll
        for (int nt = 0; nt < 4; ++nt) acc[mt][nt] = (f32x4){0.f, 0.f, 0.f, 0.f};

#pragma unroll
    for (int kstep = 0; kstep < 8; ++kstep) {
        short8 af[4], bf[4];
#pragma unroll
        for (int mt = 0; mt < 4; ++mt)
            af[mt] = *(const short8*)(xb + (mt * 16 + low) * 256 + kstep * 32 + q * 8);
#pragma unroll
        for (int nt = 0; nt < 4; ++nt)
            bf[nt] = *(const short8*)(wqp + (w * 64 + nt * 16 + low) * 256 + kstep * 32 + q * 8);
#pragma unroll
        for (int mt = 0; mt < 4; ++mt)
#pragma unroll
            for (int nt = 0; nt < 4; ++nt)
                acc[mt][nt] = mfma_k32(af[mt], bf[nt], acc[mt][nt]);
    }
    // D: px = mt*16 + q*4 + r, oc = w*64 + nt*16 + low.
    // Tb[px][h 8][c 32] pitch 256 shorts; 16B-granule index XOR (px&7).
#pragma unroll
    for (int mt = 0; mt < 4; ++mt)
#pragma unroll
        for (int nt = 0; nt < 4; ++nt) {
            int oc = w * 64 + nt * 16 + low;
            int h8 = oc & 7, cc = oc >> 3;
            int gi = h8 * 4 + (cc >> 3);          // 16B granule 0..31 within row
#pragma unroll
            for (int r = 0; r < 4; ++r) {
                int px = mt * 16 + q * 4 + r;
                Tb[px * 256 + ((gi ^ (px & 7)) * 8) + (cc & 7)] =
                    f2h(acc[mt][nt][r] + bqv[nt]);
            }
        }
    __syncthreads();
#pragma unroll
    for (int i = 0; i < 8; ++i) {
        int g = i * 256 + t;            // 2048 chunks of 16B
        int pxl = g >> 5, g16 = g & 31; // g16 = hh*4 + oct
        int hh = g16 >> 2, oct = g16 & 3;
        short8 v = *(const short8*)(Tb + pxl * 256 + ((g16 ^ (pxl & 7)) * 8));
        *(short8*)(qp + (((long)(b * 8 + hh) * 16384) + px0 + pxl) * 32 + oct * 8) = v;
    }
}

// ---------------- fused attention (v5: two-pass QK^T, lean VGPR) ----------------
// grid 4096 = 4b * 8h * 128 tiles of 128px; block 256 thr = 4 waves x 32 px.
// K staged in LDS [key][c]; V staged in LDS [c][key] pitch 264.
// Pass 1: 16 MFMAs, fold fmax (no d[16] array) -> row max via 2 shfl.
// Pass 2: recompute MFMAs, fused exp/pack/sum -> pk[16] (32 VGPR).
// P feeds PV directly as 16x16x16 B-operand; V A-frags from LDS.
__global__ __launch_bounds__(256) void k_attn(const short* __restrict__ qp,
                                              const short* __restrict__ kp,
                                              const short* __restrict__ vp,
                                              float* __restrict__ out) {
    __shared__ short Kl[256 * 32];   // 16 KB, straight copy of kp tile
    __shared__ short Vl[32 * 264];   // 16.9 KB
    int bi = blockIdx.x;
    int tile = bi & 127, h = (bi >> 7) & 7, b = bi >> 10;
    int bh = b * 8 + h;
    long px0 = (long)tile * 128;
    int t = threadIdx.x, l = t & 63, w = t >> 6;
    int low = l & 15, q = l >> 4;

    const short* kbase = kp + (long)bh * 8192;    // [key 256][c 32]
    const short* vbase = vp + (long)bh * 8192;    // [c 32][key 256]
    const short* qbase = qp + (long)bh * 16384 * 32;  // [px][c 32]

    // stage K -> LDS (straight 16KB copy, coalesced)
#pragma unroll
    for (int i = 0; i < 4; ++i) {
        int g = i * 256 + t;
        *(short8*)(Kl + g * 8) = *(const short8*)(kbase + g * 8);
    }
    // stage V -> LDS (pitch 264)
#pragma unroll
    for (int i = 0; i < 4; ++i) {
        int g = i * 256 + t;
        int c = g >> 5, k8 = g & 31;
        *(short8*)(Vl + c * 264 + k8 * 8) = *(const short8*)(vbase + c * 256 + k8 * 8);
    }
    // both q B-frags upfront (16B contiguous each; k = c = q*8+j)
    short8 bq2[2];
#pragma unroll
    for (int nt = 0; nt < 2; ++nt) {
        long px = px0 + w * 32 + nt * 16 + low;
        bq2[nt] = *(const short8*)(qbase + px * 32 + q * 8);
    }
    __syncthreads();

#pragma unroll 1
    for (int nt = 0; nt < 2; ++nt) {
        // pass 1: row max (d dies each iteration -> no 64-VGPR array)
        float m = -1e30f;
#pragma unroll
        for (int mt = 0; mt < 16; ++mt) {
            short8 ak = *(const short8*)(Kl + (mt * 16 + low) * 32 + q * 8);
            f32x4 d = mfma_k32(ak, bq2[nt], (f32x4){0.f, 0.f, 0.f, 0.f});
            m = fmaxf(m, fmaxf(fmaxf(d[0], d[1]), fmaxf(d[2], d[3])));
        }
        m = fmaxf(m, __shfl_xor(m, 16));
        m = fmaxf(m, __shfl_xor(m, 32));

        // pass 2: recompute, exp, pack, sum
        float s = 0.f;
        uint2v pk[16];
#pragma unroll
        for (int mt = 0; mt < 16; ++mt) {
            short8 ak = *(const short8*)(Kl + (mt * 16 + low) * 32 + q * 8);
            f32x4 d = mfma_k32(ak, bq2[nt], (f32x4){0.f, 0.f, 0.f, 0.f});
            float p0 = __expf(d[0] - m);
            float p1 = __expf(d[1] - m);
            float p2 = __expf(d[2] - m);
            float p3 = __expf(d[3] - m);
            s += (p0 + p1) + (p2 + p3);
            pk[mt][0] = __builtin_bit_cast(unsigned int,
                          __builtin_amdgcn_cvt_pkrtz(p0, p1));
            pk[mt][1] = __builtin_bit_cast(unsigned int,
                          __builtin_amdgcn_cvt_pkrtz(p2, p3));
        }
        s += __shfl_xor(s, 16);
        s += __shfl_xor(s, 32);
        float inv = 1.0f / s;

        // PV: o2[ct] = sum_kc V^T[c][16keys] x P[16keys][px]  (16x16x16)
        f32x4 o2[2];
        o2[0] = (f32x4){0.f, 0.f, 0.f, 0.f};
        o2[1] = (f32x4){0.f, 0.f, 0.f, 0.f};
#pragma unroll
        for (int kc = 0; kc < 16; ++kc) {
            half4 pb = __builtin_bit_cast(half4, pk[kc]);
#pragma unroll
            for (int ct = 0; ct < 2; ++ct) {
                half4 av = __builtin_bit_cast(half4,
                    *(const sh4*)(Vl + (ct * 16 + low) * 264 + kc * 16 + q * 4));
                o2[ct] = mfma_k16(av, pb, o2[ct]);
            }
        }
        // write out [b][c*8+h][px] fp32; D row=c=ct*16+q*4+r, col=px
        long px = px0 + w * 32 + nt * 16 + low;
#pragma unroll
        for (int ct = 0; ct < 2; ++ct)
#pragma unroll
            for (int r = 0; r < 4; ++r) {
                int c = ct * 16 + q * 4 + r;
                out[(((long)(b * 256 + c * 8 + h)) << 14) + px] = o2[ct][r] * inv;
            }
    }
}

// ---------------- launch ----------------
extern "C" void kernel_launch(void* const* d_in, const int* in_sizes, int n_in,
                              void* d_out, int out_size, void* d_ws, size_t ws_size,
                              hipStream_t stream) {
    const float* x  = (const float*)d_in[0];
    const float* Wq = (const float*)d_in[1];
    const float* bq = (const float*)d_in[2];
    const float* Wk = (const float*)d_in[3];
    const float* bk = (const float*)d_in[4];
    const float* Wv = (const float*)d_in[5];
    const float* bv = (const float*)d_in[6];
    float* out = (float*)d_out;

    char* ws = (char*)d_ws;
    const size_t OFF_XN = 0;             // 33,554,432  x NHWC f16
    const size_t OFF_Q  = 33554432;      // 33,554,432  q [b][h][px][c] f16
    const size_t OFF_WP = 67108864;      // 16,777,216  w_pack [512][16384] f16
    const size_t OFF_WQ = 83886080;      //    131,072  wq f16
    const size_t OFF_KP = 84017152;      //    524,288  k_pack f16
    const size_t OFF_VP = 84541440;      //    524,288  v_pack f16
    const size_t OFF_PT = 85065728;      // 16,777,216  partials fp32 [8][1024][512]
    const size_t NEEDED = 118620160;
    if (ws_size < NEEDED) return;        // fail loudly via validation

    short* xn  = (short*)(ws + OFF_XN);
    short* qp  = (short*)(ws + OFF_Q);
    short* wp  = (short*)(ws + OFF_WP);
    short* wqp = (short*)(ws + OFF_WQ);
    short* kp  = (short*)(ws + OFF_KP);
    short* vp  = (short*)(ws + OFF_VP);
    float* part= (float*)(ws + OFF_PT);

    k_pack_x <<<dim3(4096), dim3(256), 0, stream>>>(x, xn);
    k_pack_w <<<dim3(2048), dim3(256), 0, stream>>>(Wk, Wv, wp);
    k_pack_wq<<<dim3(256),  dim3(256), 0, stream>>>(Wq, wqp);
    k_kv_gemm<<<dim3(256),  dim3(256), 0, stream>>>(xn, wp, part);
    k_kv_fin <<<dim3(2048), dim3(256), 0, stream>>>(part, bk, bv, kp, vp);
    k_q_gemm <<<dim3(1024), dim3(256), 0, stream>>>(xn, wqp, bq, qp);
    k_attn   <<<dim3(4096), dim3(256), 0, stream>>>(qp, kp, vp, out);
}

// Round 12
// 169.840 us; speedup vs baseline: 1.5802x; 1.0487x over previous
//
#include <hip/hip_runtime.h>
#include <stdint.h>

// ---------------- types & helpers ----------------
typedef short sh4 __attribute__((ext_vector_type(4)));
typedef short short8 __attribute__((ext_vector_type(8)));
typedef float f32x4 __attribute__((ext_vector_type(4)));
typedef _Float16 half4 __attribute__((ext_vector_type(4)));
typedef _Float16 half8 __attribute__((ext_vector_type(8)));
typedef unsigned int uint2v __attribute__((ext_vector_type(2)));

__device__ __forceinline__ short f2h(float f) {
    _Float16 h = (_Float16)f;
    return __builtin_bit_cast(short, h);
}

__device__ __forceinline__ f32x4 mfma_k32(short8 a, short8 b, f32x4 c) {
    return __builtin_amdgcn_mfma_f32_16x16x32_f16(
        __builtin_bit_cast(half8, a), __builtin_bit_cast(half8, b), c, 0, 0, 0);
}
__device__ __forceinline__ f32x4 mfma_k16(half4 a, half4 b, f32x4 c) {
    return __builtin_amdgcn_mfma_f32_16x16x16f16(a, b, c, 0, 0, 0);
}
__device__ __forceinline__ unsigned int pkrtz(float a, float b) {
    return __builtin_bit_cast(unsigned int, __builtin_amdgcn_cvt_pkrtz(a, b));
}

// Problem constants: B=4, C=256, H=W=128 (PX=16384), inner=256, heads=8, c/head=32,
// patch=8 -> keys=256, conv K-dim = 256*64 = 16384.
// NOTE (r6): logit std ~4.6, row max ~25 -> per-row max subtraction REQUIRED.
// NOTE (r9-r11): f16 logit stash (pack logits with cvt_pkrtz, exp from stash)
// produces wrong results (bit-identical absmax 13.03 across 3 variants; pitch
// and denominator ruled out by bisection). DO NOT stash logits in f16 —
// k_attn must use the two-pass QK^T (recompute) structure below.

// ---------------- pack kernels: 64x64 fp32 tile transpose -> f16 ----------------
__device__ __forceinline__ void transpose64(const float* __restrict__ src,
                                            short* __restrict__ dst,
                                            int srcSlowStride, int dstRowStride) {
    __shared__ float tile[64][65];
    const int t = threadIdx.x;
#pragma unroll
    for (int i = 0; i < 16; ++i) {
        int idx = i * 256 + t;
        int fast = idx & 63, slow = idx >> 6;
        tile[slow][fast] = src[(long)slow * srcSlowStride + fast];
    }
    __syncthreads();
#pragma unroll
    for (int i = 0; i < 2; ++i) {
        int ch = i * 256 + t;
        int fast = ch >> 3, sg = ch & 7;
        short8 v;
#pragma unroll
        for (int j = 0; j < 8; ++j) v[j] = f2h(tile[sg * 8 + j][fast]);
        *(short8*)(dst + (long)fast * dstRowStride + sg * 8) = v;
    }
}

// x: [4][256][16384] fp32 (NCHW) -> xn: [4][16384][256] f16 (NHWC)
__global__ __launch_bounds__(256) void k_pack_x(const float* __restrict__ x,
                                                short* __restrict__ xn) {
    int bi = blockIdx.x;                 // 4096 = 4b * 256pxt * 4ct
    int ct = bi & 3, pxt = (bi >> 2) & 255, b = bi >> 10;
    const float* src = x + (((long)(b * 256 + ct * 64)) << 14) + (long)pxt * 64;
    short* dst = xn + (((long)(b << 14) + pxt * 64) * 256) + ct * 64;
    transpose64(src, dst, 16384, 256);
}

// Wk/Wv: [256][256][64] fp32 -> wp: [512][64][256] f16 (oc<256: k, else v), K order (dydx, c)
__global__ __launch_bounds__(256) void k_pack_w(const float* __restrict__ wk,
                                                const float* __restrict__ wv,
                                                short* __restrict__ wp) {
    int bi = blockIdx.x;                 // 2048 = 512oc * 4ct
    int ct = bi & 3, oc = bi >> 2;
    const float* base = (oc < 256) ? (wk + (long)oc * 16384) : (wv + (long)(oc - 256) * 16384);
    const float* src = base + ct * 4096; // + c0*64
    short* dst = wp + (long)oc * 16384 + ct * 64;
    transpose64(src, dst, 64, 256);
}

// Wq: [256][256] fp32 -> f16 (layout preserved: [oc][c])
__global__ __launch_bounds__(256) void k_pack_wq(const float* __restrict__ wq,
                                                 short* __restrict__ wqp) {
    int i = blockIdx.x * 256 + threadIdx.x; // grid 256 -> 65536
    wqp[i] = f2h(wq[i]);
}

// ---------------- K/V conv as GEMM (v3: 128x64 tile, 512 blocks, 2/CU) ----
// C[patch 1024][oc 512] = A[patch][k 16384] * B[k][oc]
// grid 512 = 8kc * 8pm * 8nb; block 256 thr (4 waves); Kchunk 2048 (32 x BK=64).
// r8's 256-block version was 1 block/CU -> barrier drains idled the CU; 2/CU
// lets blocks overlap each other's staging/compute phases.
__global__ __launch_bounds__(256) void k_kv_gemm(const short* __restrict__ xn,
                                                 const short* __restrict__ wp,
                                                 float* __restrict__ part) {
    __shared__ short Al[128 * 64]; // rows 128B = 8 granules, swizzled
    __shared__ short Bl[64 * 64];
    int bid = blockIdx.x;                       // 512
    int wg = (bid & 7) * 64 + (bid >> 3);       // XCD-contiguous swizzle (512 = 8*64)
    int nb = wg & 7, pm = (wg >> 3) & 7, kc = wg >> 6;
    int t = threadIdx.x, l = t & 63, w = t >> 6;
    int wm = w >> 1, wn = w & 1;
    int low = l & 15, q = l >> 4;

    f32x4 acc[4][2];
#pragma unroll
    for (int mt = 0; mt < 4; ++mt)
#pragma unroll
        for (int nt = 0; nt < 2; ++nt) acc[mt][nt] = (f32x4){0.f, 0.f, 0.f, 0.f};

    for (int kk = 0; kk < 32; ++kk) {
        short8 va[4], vb[2];
#pragma unroll
        for (int i = 0; i < 4; ++i) {           // A: 1024 granules (128 rows x 8)
            int g = i * 256 + t;
            int row = g >> 3, lg = g & 7;
            int patch = pm * 128 + row;
            int kg = kc * 2048 + kk * 64 + lg * 8;
            int dydx = kg >> 8, cc = kg & 255;
            int bb = patch >> 8, pid = patch & 255;
            int ph = pid >> 4, pw = pid & 15;
            int px = (ph * 8 + (dydx >> 3)) * 128 + pw * 8 + (dydx & 7);
            va[i] = *(const short8*)(xn + ((long)(bb << 14) + px) * 256 + cc);
        }
#pragma unroll
        for (int i = 0; i < 2; ++i) {           // B: 512 granules (64 rows x 8)
            int g = i * 256 + t;
            int row = g >> 3, lg = g & 7;
            int oc = nb * 64 + row;
            int kg = kc * 2048 + kk * 64 + lg * 8;
            vb[i] = *(const short8*)(wp + (long)oc * 16384 + kg);
        }
#pragma unroll
        for (int i = 0; i < 4; ++i) {
            int g = i * 256 + t;
            int row = g >> 3, lg = g & 7;
            *(short8*)(Al + row * 64 + ((lg ^ (row & 7)) * 8)) = va[i];
        }
#pragma unroll
        for (int i = 0; i < 2; ++i) {
            int g = i * 256 + t;
            int row = g >> 3, lg = g & 7;
            *(short8*)(Bl + row * 64 + ((lg ^ (row & 7)) * 8)) = vb[i];
        }
        __syncthreads();
#pragma unroll
        for (int ks = 0; ks < 2; ++ks) {
            short8 af[4], bf[2];
#pragma unroll
            for (int mt = 0; mt < 4; ++mt) {
                int row = wm * 64 + mt * 16 + low;
                int lg = ks * 4 + q;
                af[mt] = *(const short8*)(Al + row * 64 + ((lg ^ (row & 7)) * 8));
            }
#pragma unroll
            for (int nt = 0; nt < 2; ++nt) {
                int row = wn * 32 + nt * 16 + low;
                int lg = ks * 4 + q;
                bf[nt] = *(const short8*)(Bl + row * 64 + ((lg ^ (row & 7)) * 8));
            }
#pragma unroll
            for (int mt = 0; mt < 4; ++mt)
#pragma unroll
                for (int nt = 0; nt < 2; ++nt)
                    acc[mt][nt] = mfma_k32(af[mt], bf[nt], acc[mt][nt]);
        }
        __syncthreads();
    }
    // D: row(patch) = q*4+r (+16mt+64wm+128pm), col(oc) = low (+16nt+32wn+64nb)
#pragma unroll
    for (int mt = 0; mt < 4; ++mt) {
        int patch = pm * 128 + wm * 64 + mt * 16 + q * 4;
#pragma unroll
        for (int nt = 0; nt < 2; ++nt) {
            int oc = nb * 64 + wn * 32 + nt * 16 + low;
#pragma unroll
            for (int r = 0; r < 4; ++r)
                part[((long)kc * 1024 + patch + r) * 512 + oc] = acc[mt][nt][r];
        }
    }
}

// reduce partials, add bias, pack k -> [b][h][key][c], v -> [b][h][c][key] (f16)
__global__ __launch_bounds__(256) void k_kv_fin(const float* __restrict__ part,
                                                const float* __restrict__ bk,
                                                const float* __restrict__ bv,
                                                short* __restrict__ kp,
                                                short* __restrict__ vp) {
    int idx = blockIdx.x * 256 + threadIdx.x;   // 524288 = 1024patch * 512oc
    int oc = idx & 511, patch = idx >> 9;
    float s = 0.f;
#pragma unroll
    for (int kc = 0; kc < 8; ++kc) s += part[(long)kc * 524288 + idx];
    int b = patch >> 8, key = patch & 255;
    if (oc < 256) {
        s += bk[oc];
        kp[(((long)(b * 8 + (oc & 7)) * 256) + key) * 32 + (oc >> 3)] = f2h(s);
    } else {
        int o = oc - 256;
        s += bv[o];
        vp[(((long)(b * 8 + (o & 7)) * 32) + (o >> 3)) * 256 + key] = f2h(s);
    }
}

// ---------------- Q conv (1x1) as GEMM (no staging LDS, D[px][oc]) -------
// A-frag = xn[px][c] (16B contiguous per lane), B-frag = wqp[oc][c] (L2-hot).
// grid 1024 = 4b * 256 tiles of 64px; block 256 thr = 4 waves; wave w owns
// oc in [64w, 64w+64). LDS only for the output transpose (32KB -> 4 blocks/CU).
// q stored as [b][h 8][px 16384][c 32] f16 (attention reads 16B per lane).
__global__ __launch_bounds__(256) void k_q_gemm(const short* __restrict__ xn,
                                                const short* __restrict__ wqp,
                                                const float* __restrict__ bq,
                                                short* __restrict__ qp) {
    __shared__ short Tb[64 * 256];  // 32 KB
    int bi = blockIdx.x;            // 1024 = 4b * 256 tiles
    int b = bi >> 8, tile = bi & 255;
    long px0 = (long)tile * 64;
    int t = threadIdx.x, l = t & 63, w = t >> 6;
    int low = l & 15, q = l >> 4;

    const short* xb = xn + (((long)(b << 14)) + px0) * 256;

    float bqv[4];
#pragma unroll
    for (int nt = 0; nt < 4; ++nt) bqv[nt] = bq[w * 64 + nt * 16 + low];

    f32x4 acc[4][4];   // [mt: px][nt: oc]
#pragma unroll
    for (int mt = 0; mt < 4; ++mt)
#pragma unroll
        for (int nt = 0; nt < 4; ++nt) acc[mt][nt] = (f32x4){0.f, 0.f, 0.f, 0.f};

#pragma unroll
    for (int kstep = 0; kstep < 8; ++kstep) {
        short8 af[4], bf[4];
#pragma unroll
        for (int mt = 0; mt < 4; ++mt)
            af[mt] = *(const short8*)(xb + (mt * 16 + low) * 256 + kstep * 32 + q * 8);
#pragma unroll
        for (int nt = 0; nt < 4; ++nt)
            bf[nt] = *(const short8*)(wqp + (w * 64 + nt * 16 + low) * 256 + kstep * 32 + q * 8);
#pragma unroll
        for (int mt = 0; mt < 4; ++mt)
#pragma unroll
            for (int nt = 0; nt < 4; ++nt)
                acc[mt][nt] = mfma_k32(af[mt], bf[nt], acc[mt][nt]);
    }
    // D: px = mt*16 + q*4 + r, oc = w*64 + nt*16 + low.
    // Tb[px][h 8][c 32] pitch 256 shorts; 16B-granule index XOR (px&7).
#pragma unroll
    for (int mt = 0; mt < 4; ++mt)
#pragma unroll
        for (int nt = 0; nt < 4; ++nt) {
            int oc = w * 64 + nt * 16 + low;
            int h8 = oc & 7, cc = oc >> 3;
            int gi = h8 * 4 + (cc >> 3);          // 16B granule 0..31 within row
#pragma unroll
            for (int r = 0; r < 4; ++r) {
                int px = mt * 16 + q * 4 + r;
                Tb[px * 256 + ((gi ^ (px & 7)) * 8) + (cc & 7)] =
                    f2h(acc[mt][nt][r] + bqv[nt]);
            }
        }
    __syncthreads();
#pragma unroll
    for (int i = 0; i < 8; ++i) {
        int g = i * 256 + t;            // 2048 chunks of 16B
        int pxl = g >> 5, g16 = g & 31; // g16 = hh*4 + oct
        int hh = g16 >> 2, oct = g16 & 3;
        short8 v = *(const short8*)(Tb + pxl * 256 + ((g16 ^ (pxl & 7)) * 8));
        *(short8*)(qp + (((long)(b * 8 + hh) * 16384) + px0 + pxl) * 32 + oct * 8) = v;
    }
}

// ---------------- fused attention (r8-verified two-pass version, reverted) ----
// grid 4096 = 4b * 8h * 128 tiles of 128px; block 256 thr = 4 waves x 32 px.
// K staged in LDS [key][c]; V staged in LDS [c][key] pitch 264.
// Pass 1: 16 MFMAs, fold fmax (no d[16] array) -> row max via 2 shfl.
// Pass 2: recompute MFMAs, fused exp/pack/sum -> pk[16] (32 VGPR).
// P feeds PV directly as 16x16x16 B-operand; V A-frags from LDS.
__global__ __launch_bounds__(256) void k_attn(const short* __restrict__ qp,
                                              const short* __restrict__ kp,
                                              const short* __restrict__ vp,
                                              float* __restrict__ out) {
    __shared__ short Kl[256 * 32];   // 16 KB, straight copy of kp tile
    __shared__ short Vl[32 * 264];   // 16.9 KB
    int bi = blockIdx.x;
    int tile = bi & 127, h = (bi >> 7) & 7, b = bi >> 10;
    int bh = b * 8 + h;
    long px0 = (long)tile * 128;
    int t = threadIdx.x, l = t & 63, w = t >> 6;
    int low = l & 15, q = l >> 4;

    const short* kbase = kp + (long)bh * 8192;    // [key 256][c 32]
    const short* vbase = vp + (long)bh * 8192;    // [c 32][key 256]
    const short* qbase = qp + (long)bh * 16384 * 32;  // [px][c 32]

    // stage K -> LDS (straight 16KB copy, coalesced)
#pragma unroll
    for (int i = 0; i < 4; ++i) {
        int g = i * 256 + t;
        *(short8*)(Kl + g * 8) = *(const short8*)(kbase + g * 8);
    }
    // stage V -> LDS (pitch 264)
#pragma unroll
    for (int i = 0; i < 4; ++i) {
        int g = i * 256 + t;
        int c = g >> 5, k8 = g & 31;
        *(short8*)(Vl + c * 264 + k8 * 8) = *(const short8*)(vbase + c * 256 + k8 * 8);
    }
    // both q B-frags upfront (16B contiguous each; k = c = q*8+j)
    short8 bq2[2];
#pragma unroll
    for (int nt = 0; nt < 2; ++nt) {
        long px = px0 + w * 32 + nt * 16 + low;
        bq2[nt] = *(const short8*)(qbase + px * 32 + q * 8);
    }
    __syncthreads();

#pragma unroll 1
    for (int nt = 0; nt < 2; ++nt) {
        // pass 1: row max (d dies each iteration -> no 64-VGPR array)
        float m = -1e30f;
#pragma unroll
        for (int mt = 0; mt < 16; ++mt) {
            short8 ak = *(const short8*)(Kl + (mt * 16 + low) * 32 + q * 8);
            f32x4 d = mfma_k32(ak, bq2[nt], (f32x4){0.f, 0.f, 0.f, 0.f});
            m = fmaxf(m, fmaxf(fmaxf(d[0], d[1]), fmaxf(d[2], d[3])));
        }
        m = fmaxf(m, __shfl_xor(m, 16));
        m = fmaxf(m, __shfl_xor(m, 32));

        // pass 2: recompute, exp, pack, sum
        float s = 0.f;
        uint2v pk[16];
#pragma unroll
        for (int mt = 0; mt < 16; ++mt) {
            short8 ak = *(const short8*)(Kl + (mt * 16 + low) * 32 + q * 8);
            f32x4 d = mfma_k32(ak, bq2[nt], (f32x4){0.f, 0.f, 0.f, 0.f});
            float p0 = __expf(d[0] - m);
            float p1 = __expf(d[1] - m);
            float p2 = __expf(d[2] - m);
            float p3 = __expf(d[3] - m);
            s += (p0 + p1) + (p2 + p3);
            pk[mt][0] = pkrtz(p0, p1);
            pk[mt][1] = pkrtz(p2, p3);
        }
        s += __shfl_xor(s, 16);
        s += __shfl_xor(s, 32);
        float inv = 1.0f / s;

        // PV: o2[ct] = sum_kc V^T[c][16keys] x P[16keys][px]  (16x16x16)
        f32x4 o2[2];
        o2[0] = (f32x4){0.f, 0.f, 0.f, 0.f};
        o2[1] = (f32x4){0.f, 0.f, 0.f, 0.f};
#pragma unroll
        for (int kc = 0; kc < 16; ++kc) {
            half4 pb = __builtin_bit_cast(half4, pk[kc]);
#pragma unroll
            for (int ct = 0; ct < 2; ++ct) {
                half4 av = __builtin_bit_cast(half4,
                    *(const sh4*)(Vl + (ct * 16 + low) * 264 + kc * 16 + q * 4));
                o2[ct] = mfma_k16(av, pb, o2[ct]);
            }
        }
        // write out [b][c*8+h][px] fp32; D row=c=ct*16+q*4+r, col=px
        long px = px0 + w * 32 + nt * 16 + low;
#pragma unroll
        for (int ct = 0; ct < 2; ++ct)
#pragma unroll
            for (int r = 0; r < 4; ++r) {
                int c = ct * 16 + q * 4 + r;
                out[(((long)(b * 256 + c * 8 + h)) << 14) + px] = o2[ct][r] * inv;
            }
    }
}

// ---------------- launch ----------------
extern "C" void kernel_launch(void* const* d_in, const int* in_sizes, int n_in,
                              void* d_out, int out_size, void* d_ws, size_t ws_size,
                              hipStream_t stream) {
    const float* x  = (const float*)d_in[0];
    const float* Wq = (const float*)d_in[1];
    const float* bq = (const float*)d_in[2];
    const float* Wk = (const float*)d_in[3];
    const float* bk = (const float*)d_in[4];
    const float* Wv = (const float*)d_in[5];
    const float* bv = (const float*)d_in[6];
    float* out = (float*)d_out;

    char* ws = (char*)d_ws;
    const size_t OFF_XN = 0;             // 33,554,432  x NHWC f16
    const size_t OFF_Q  = 33554432;      // 33,554,432  q [b][h][px][c] f16
    const size_t OFF_WP = 67108864;      // 16,777,216  w_pack [512][16384] f16
    const size_t OFF_WQ = 83886080;      //    131,072  wq f16
    const size_t OFF_KP = 84017152;      //    524,288  k_pack f16
    const size_t OFF_VP = 84541440;      //    524,288  v_pack f16
    const size_t OFF_PT = 85065728;      // 16,777,216  partials fp32 [8][1024][512]
    const size_t NEEDED = 118620160;
    if (ws_size < NEEDED) return;        // fail loudly via validation

    short* xn  = (short*)(ws + OFF_XN);
    short* qp  = (short*)(ws + OFF_Q);
    short* wp  = (short*)(ws + OFF_WP);
    short* wqp = (short*)(ws + OFF_WQ);
    short* kp  = (short*)(ws + OFF_KP);
    short* vp  = (short*)(ws + OFF_VP);
    float* part= (float*)(ws + OFF_PT);

    k_pack_x <<<dim3(4096), dim3(256), 0, stream>>>(x, xn);
    k_pack_w <<<dim3(2048), dim3(256), 0, stream>>>(Wk, Wv, wp);
    k_pack_wq<<<dim3(256),  dim3(256), 0, stream>>>(Wq, wqp);
    k_kv_gemm<<<dim3(512),  dim3(256), 0, stream>>>(xn, wp, part);
    k_kv_fin <<<dim3(2048), dim3(256), 0, stream>>>(part, bk, bv, kp, vp);
    k_q_gemm <<<dim3(1024), dim3(256), 0, stream>>>(xn, wqp, bq, qp);
    k_attn   <<<dim3(4096), dim3(256), 0, stream>>>(qp, kp, vp, out);
}